// Round 11
// baseline (719.533 us; speedup 1.0000x reference)
//
#include <hip/hip_runtime.h>
#include <math.h>

#define B 4096
#define D 512
#define TOPK 32

constexpr float OT_EPS_F = 0.05f;
constexpr float FLOORK   = 1e-12f;
constexpr float AMASS    = 1.0f / 4096.0f;   // exact 2^-12
constexpr float TAU      = 1.8f;             // k1 candidate prefilter threshold
constexpr float EPS_C    = 3.814697e-6f;     // 2^-18 convergence tolerance

__device__ __forceinline__ float softplusf(float x) {
    return fmaxf(x, 0.0f) + log1pf(expf(-fabsf(x)));
}
__device__ __forceinline__ unsigned int fkey(float f) {
    unsigned int x = __float_as_uint(f);
    return x ^ ((x & 0x80000000u) ? 0xFFFFFFFFu : 0x80000000u);
}
__device__ __forceinline__ float finv(unsigned int k) {
    unsigned int x = (k & 0x80000000u) ? (k ^ 0x80000000u) : ~k;
    return __uint_as_float(x);
}
__device__ __forceinline__ float rcpf_(float x) { return __builtin_amdgcn_rcpf(x); }
__device__ __forceinline__ void lgkm0() {
    asm volatile("s_waitcnt lgkmcnt(0)" ::: "memory");
    __builtin_amdgcn_sched_barrier(0);
}
__device__ __forceinline__ void vm0() {
    asm volatile("s_waitcnt vmcnt(0)" ::: "memory");
}
#define DPPADD(x, ctrl) ((x) + __int_as_float(__builtin_amdgcn_update_dpp(0, __float_as_int(x), (ctrl), 0xf, 0xf, false)))
__device__ __forceinline__ float wsum64(float x) {
    x = DPPADD(x, 0x111);
    x = DPPADD(x, 0x112);
    x = DPPADD(x, 0x114);
    x = DPPADD(x, 0x118);
    x = DPPADD(x, 0x142);
    x = DPPADD(x, 0x143);
    return __int_as_float(__builtin_amdgcn_readlane(__float_as_int(x), 63));
}

// ---------------------------------------------------------------------------
// k1: wave-per-row (4 rows / 256-block). Ballot-based exact top-32 +
// base-loss partial + row max + fused ratio sample. Unchanged from round 10.
// ---------------------------------------------------------------------------
__global__ __launch_bounds__(256) void k1_row(const float* __restrict__ logits,
                                              const float* __restrict__ text,
                                              const float* __restrict__ image,
                                              const float* __restrict__ bias_p,
                                              float* __restrict__ rowsum,
                                              unsigned int* __restrict__ rowmaxk,
                                              int* __restrict__ top_idx,
                                              float* __restrict__ top_z,
                                              float* __restrict__ ratio,
                                              unsigned int* __restrict__ flags) {
    __shared__ unsigned int candk[4][128];
    __shared__ unsigned int candi[4][128];
    __shared__ unsigned int wcnt[4];

    const int tid = threadIdx.x, w = tid >> 6, lane = tid & 63;
    const int row = (blockIdx.x << 2) + w;
    const float bias = bias_p[0];
    const float* lr = logits + (size_t)row * B;
    const float4* lr4 = (const float4*)lr;

    if (lane == 0) wcnt[w] = 0;
    candk[w][lane] = 0; candk[w][lane + 64] = 0;

    float lsum = 0.0f, lmax = -INFINITY;
    bool ovf = false;

#define K1ELEM(ZV, CC) do {                                                   \
        float z_ = (ZV) + bias;                                               \
        bool dg_ = ((CC) == row);                                             \
        lsum += dg_ ? softplusf(-z_) : softplusf(z_);                         \
        float zm_ = dg_ ? -INFINITY : z_;                                     \
        lmax = fmaxf(lmax, zm_);                                              \
        if (zm_ > TAU) {                                                      \
            unsigned int p_ = atomicAdd(&wcnt[w], 1u);                        \
            if (p_ < 128u) { candk[w][p_] = fkey(zm_);                        \
                             candi[w][p_] = (unsigned int)(CC); }             \
            else ovf = true;                                                  \
        } } while (0)

    #pragma unroll
    for (int t = 0; t < 16; ++t) {
        float4 z4 = lr4[lane + (t << 6)];
        int cb = (lane << 2) + (t << 8);
        K1ELEM(z4.x, cb);
        K1ELEM(z4.y, cb + 1);
        K1ELEM(z4.z, cb + 2);
        K1ELEM(z4.w, cb + 3);
    }
#undef K1ELEM
    __syncthreads();

    for (int o = 1; o < 64; o <<= 1) {
        lsum += __shfl_xor(lsum, o);
        lmax = fmaxf(lmax, __shfl_xor(lmax, o));
    }
    if (lane == 0) { rowsum[row] = lsum; rowmaxk[row] = fkey(lmax); }

    const unsigned int n = wcnt[w];
    bool fb = (n < (unsigned)TOPK) || (n > 128u) || (__ballot(ovf) != 0ull);

    const unsigned int c0k = candk[w][lane], c1k = candk[w][lane + 64];
    const unsigned int i0  = candi[w][lane], i1  = candi[w][lane + 64];

    if (!fb) {
        unsigned int K = 0u;
        for (int b = 31; b >= 0; --b) {
            unsigned int tr = K | (1u << b);
            int cnt = __popcll(__ballot(c0k >= tr)) + __popcll(__ballot(c1k >= tr));
            if (cnt >= TOPK) K = tr;
        }
        unsigned long long m0g = __ballot(c0k > K), m1g = __ballot(c1k > K);
        unsigned long long m0e = __ballot(c0k == K), m1e = __ballot(c1k == K);
        int cnt_gt = __popcll(m0g) + __popcll(m1g);
        int kneed  = TOPK - cnt_gt;
        int eqc    = __popcll(m0e) + __popcll(m1e);
        if (eqc != kneed) {
            fb = true;
        } else {
            unsigned long long lmlt = (1ull << lane) - 1ull;
            size_t rb = (size_t)row * TOPK;
            int r0 = __popcll(m0g & lmlt);
            if (c0k > K) { top_idx[rb + r0] = (int)i0; top_z[rb + r0] = finv(c0k); }
            int r1 = __popcll(m0g) + __popcll(m1g & lmlt);
            if (c1k > K) { top_idx[rb + r1] = (int)i1; top_z[rb + r1] = finv(c1k); }
            int e0 = cnt_gt + __popcll(m0e & lmlt);
            if (c0k == K) { top_idx[rb + e0] = (int)i0; top_z[rb + e0] = finv(c0k); }
            int e1 = cnt_gt + __popcll(m0e) + __popcll(m1e & lmlt);
            if (c1k == K) { top_idx[rb + e1] = (int)i1; top_z[rb + e1] = finv(c1k); }
        }
    }
    if (fb && lane == 0) flags[row] = 1u;

    // ---- fused ratio sample ----
    unsigned int hh = (unsigned int)row * 2654435761u;
    int j = (int)(((unsigned int)row + 1u + (hh % 4095u)) & 4095u);   // j != row
    const float4* tr4 = (const float4*)(text + (size_t)row * D);
    const float4* ir4 = (const float4*)(image + (size_t)j * D);
    float4 a0 = tr4[lane], b0 = ir4[lane];
    float4 a1 = tr4[lane + 64], b1 = ir4[lane + 64];
    float s3 = a0.x * b0.x + a0.y * b0.y + a0.z * b0.z + a0.w * b0.w
             + a1.x * b1.x + a1.y * b1.y + a1.z * b1.z + a1.w * b1.w;
    for (int o = 1; o < 64; o <<= 1) s3 += __shfl_xor(s3, o);
    if (lane == 0) ratio[row] = lr[j] / (s3 + 1e-8f);
}

// ---------------------------------------------------------------------------
// k1f: exact fallback for flagged rows (LDS radix select). Normally no-op.
// ---------------------------------------------------------------------------
__global__ __launch_bounds__(256) void k1_fallback(const float* __restrict__ logits,
                                                   const float* __restrict__ bias_p,
                                                   const unsigned int* __restrict__ flags,
                                                   int* __restrict__ top_idx,
                                                   float* __restrict__ top_z) {
    const int row = blockIdx.x;
    if (flags[row] == 0u) return;

    __shared__ unsigned int skey[B];
    __shared__ unsigned int histm[4 * 257 + 4];
    __shared__ unsigned int selb, selk;
    __shared__ int cnt_gt, cnt_eq;
    __shared__ int eqi[64];

    const int tid = threadIdx.x, wid = tid >> 6, lane = tid & 63;
    const float bias = bias_p[0];
    const float* lr = logits + (size_t)row * B;

    #pragma unroll
    for (int t = 0; t < 16; ++t) {
        int c = tid + (t << 8);
        float z = lr[c] + bias;
        skey[c] = fkey((c == row) ? -INFINITY : z);
    }
    if (tid == 0) { cnt_gt = 0; cnt_eq = 0; }
    __syncthreads();

    unsigned int prefix = 0, kneed = TOPK;
    for (int r = 0; r < 4; ++r) {
        for (int i = tid; i < 4 * 257 + 4; i += 256) histm[i] = 0;
        __syncthreads();
        const int shift = 24 - 8 * r;
        #pragma unroll
        for (int t = 0; t < 16; ++t) {
            int c = tid + (t << 8);
            unsigned int kx = skey[c];
            bool part = (r == 0) || ((kx >> (32 - 8 * r)) == prefix);
            if (part) atomicAdd(&histm[wid * 257 + ((kx >> shift) & 255u)], 1u);
        }
        __syncthreads();
        unsigned int h = histm[tid] + histm[257 + tid] + histm[514 + tid] + histm[771 + tid];
        unsigned int s = h;
        for (int off = 1; off < 64; off <<= 1) {
            unsigned int o = __shfl_down(s, off);
            if (lane + off < 64) s += o;
        }
        if (lane == 0) histm[1028 + wid] = s;
        __syncthreads();
        unsigned int coarse = 0;
        for (int ww = wid + 1; ww < 4; ++ww) coarse += histm[1028 + ww];
        unsigned int incl = s + coarse, strict = incl - h;
        if (strict < kneed && kneed <= incl) { selb = (unsigned int)tid; selk = kneed - strict; }
        __syncthreads();
        prefix = (prefix << 8) | selb;
        kneed = selk;
        __syncthreads();
    }
    const unsigned int K32 = prefix;

    #pragma unroll
    for (int t = 0; t < 16; ++t) {
        int c = tid + (t << 8);
        unsigned int kx = skey[c];
        if (kx > K32) {
            int p = atomicAdd(&cnt_gt, 1);
            top_idx[(size_t)row * TOPK + p] = c;
            top_z [(size_t)row * TOPK + p] = finv(kx);
        } else if (kx == K32) {
            int p = atomicAdd(&cnt_eq, 1);
            if (p < 64) eqi[p] = c;
        }
    }
    __syncthreads();
    if (tid == 0) {
        int q = (int)kneed, base = cnt_gt, E = cnt_eq;
        float zv = finv(K32);
        if (E <= 64) {
            for (int s2 = 0; s2 < q; ++s2) {
                int best = 0x7FFFFFFF, bp = 0;
                for (int e = 0; e < E; ++e) { int ix = eqi[e]; if (ix < best) { best = ix; bp = e; } }
                eqi[bp] = 0x7FFFFFFF;
                top_idx[(size_t)row * TOPK + base + s2] = best;
                top_z [(size_t)row * TOPK + base + s2] = zv;
            }
        } else {
            int taken = 0;
            for (int c = 0; c < B && taken < q; ++c)
                if (skey[c] == K32) {
                    top_idx[(size_t)row * TOPK + base + taken] = c;
                    top_z [(size_t)row * TOPK + base + taken] = zv;
                    ++taken;
                }
        }
    }
}

// ---------------------------------------------------------------------------
// kmid: FUSED k2+k3+k3b+sinkhorn. One 256-thread block, ~22 KB LDS, small code.
//  A: reduce rowsum/rowmaxk -> M, base_acc.
//  B: build sparse list (exact e>1e-12 test), LDS + global mirror.
//  C: O(m^2) dual sort (row-major & col-major), owner flags, run counts,
//     compact row/col ids, cross-index -> per-entry table indices.
//  D: wave-0 Sinkhorn with 256-entry LDS tables (prod/q/usm/vsm), DPP sums,
//     tolerance early-exit. Epilogue: fill v0 + scatter active cols.
//  m>256 or col-run>64  ->  meta[0]=1, k4_fb handles (never for this data).
// ---------------------------------------------------------------------------
__global__ __launch_bounds__(256) void kmid(const float* __restrict__ rowsum,
                                            const unsigned int* __restrict__ rowmaxk,
                                            const float* __restrict__ top_z,
                                            const int* __restrict__ top_idx,
                                            unsigned int* __restrict__ Mkey_g,
                                            double* __restrict__ base_acc_g,
                                            unsigned int* __restrict__ mcount_g,
                                            unsigned int* __restrict__ meta_g,
                                            unsigned int* __restrict__ lij_g,
                                            float* __restrict__ lval_g,
                                            float* __restrict__ vout) {
    __shared__ double sd[4];
    __shared__ unsigned int sm4[4];
    __shared__ float sMf;
    __shared__ unsigned int mcnt;
    __shared__ unsigned int hdr[4];     // [0]=mode [1]=nr [2]=nc [3]=maxCC
    __shared__ unsigned int Aij[256];
    __shared__ float        Aval[256];
    __shared__ unsigned int sRij[256];
    __shared__ float        sRval[256];
    __shared__ unsigned int sCkey[256];  // (col<<12)|row
    __shared__ float        sCval[256];
    __shared__ unsigned int x2c[256], c2x[256];
    __shared__ unsigned int ownRl[256], ownCl[256];
    __shared__ unsigned int rridl[256], ccidl[256];
    __shared__ unsigned int vidxl[256], uidxl[256];
    __shared__ unsigned int packR[256], packC[256];
    __shared__ float prod[256], qarr[256], usm[256], vsm[256];

    const int tid = threadIdx.x, lane = tid & 63, wv = tid >> 6;

    // ---------- A: reduce ----------
    double s = 0.0; unsigned int mk = 0u;
    #pragma unroll
    for (int t = 0; t < 16; ++t) {
        int i = tid + (t << 8);
        s += (double)rowsum[i];
        unsigned int k = rowmaxk[i];
        mk = (k > mk) ? k : mk;
    }
    for (int o = 1; o < 64; o <<= 1) {
        s += __shfl_xor(s, o);
        unsigned int om = __shfl_xor(mk, o);
        mk = (om > mk) ? om : mk;
    }
    if (lane == 0) { sd[wv] = s; sm4[wv] = mk; }
    if (tid == 0) mcnt = 0u;
    __syncthreads();
    if (tid == 0) {
        double bs = sd[0] + sd[1] + sd[2] + sd[3];
        unsigned int m2 = max(max(sm4[0], sm4[1]), max(sm4[2], sm4[3]));
        *base_acc_g = bs;
        *Mkey_g = m2;
        sMf = finv(m2);
    }
    __syncthreads();
    const float M = sMf;

    // ---------- B: build sparse list ----------
    for (int c = tid; c < B * TOPK; c += 256) {
        float z = top_z[c];
        float cc = fmaxf(M - z, 0.0f);
        if (cc < 1.45f) {                          // conservative prefilter
            float e = expf(-(cc / OT_EPS_F));      // exact original expression
            if (e > FLOORK) {
                unsigned int pos = atomicAdd(&mcnt, 1u);
                unsigned int i = (unsigned int)(c >> 5);
                unsigned int j = (unsigned int)top_idx[c];
                unsigned int ij = (i << 12) | j;
                lij_g[pos] = ij; lval_g[pos] = e - FLOORK;
                if (pos < 256u) { Aij[pos] = ij; Aval[pos] = e - FLOORK; }
            }
        }
    }
    __syncthreads();
    const int m = (int)mcnt;
    if (tid == 0) mcount_g[0] = (unsigned int)m;
    if (m > 256) { if (tid == 0) meta_g[0] = 1u; return; }

    // ---------- C: dual sort + metadata ----------
    if (tid < m) {
        unsigned int key = Aij[tid]; float val = Aval[tid];
        unsigned int keyC = ((key & 4095u) << 12) | (key >> 12);
        int rR = 0, rC = 0;
        for (int j2 = 0; j2 < m; ++j2) {
            unsigned int kj = Aij[j2];
            unsigned int kjC = ((kj & 4095u) << 12) | (kj >> 12);
            rR += (kj < key); rC += (kjC < keyC);
        }
        sRij[rR] = key;  sRval[rR] = val;
        sCkey[rC] = keyC; sCval[rC] = val;
        x2c[rR] = (unsigned int)rC; c2x[rC] = (unsigned int)rR;
    }
    __syncthreads();
    unsigned int myCntR = 0, myCntC = 0;
    if (tid < m) {
        unsigned int rowK = sRij[tid] >> 12;
        unsigned int colK = sCkey[tid] >> 12;
        ownRl[tid] = (tid == 0 || (sRij[tid - 1] >> 12) != rowK) ? 1u : 0u;
        ownCl[tid] = (tid == 0 || (sCkey[tid - 1] >> 12) != colK) ? 1u : 0u;
        int cr = 0, cc2 = 0;
        for (int j2 = 0; j2 < m; ++j2) {
            cr  += ((sRij[j2] >> 12) == rowK);
            cc2 += ((sCkey[j2] >> 12) == colK);
        }
        myCntR = (unsigned int)cr; myCntC = (unsigned int)cc2;
    }
    {   // max col count
        unsigned int mcc = myCntC;
        for (int o = 1; o < 64; o <<= 1) { unsigned int t2 = __shfl_xor(mcc, o); mcc = max(mcc, t2); }
        if (lane == 0) sm4[wv] = mcc;
    }
    __syncthreads();
    if (tid < m) {
        int rr = 0, cc3 = 0;
        for (int j2 = 0; j2 <= tid; ++j2) { rr += ownRl[j2]; cc3 += ownCl[j2]; }
        rridl[tid] = (unsigned int)(rr - 1); ccidl[tid] = (unsigned int)(cc3 - 1);
    }
    if (tid == 0) {
        unsigned int mx = max(max(sm4[0], sm4[1]), max(sm4[2], sm4[3]));
        hdr[3] = mx;
        hdr[0] = (mx > 64u) ? 1u : 0u;
        meta_g[0] = hdr[0];
    }
    __syncthreads();
    if (hdr[0]) return;   // uniform: fallback kernel handles
    if (tid < m) {
        vidxl[tid] = ccidl[x2c[tid]];
        uidxl[tid] = rridl[c2x[tid]];
        unsigned int pr = 0u, pc = 0u;
        if (ownRl[tid]) pr = 0x80000000u | (rridl[tid] << 8) | myCntR;
        if (ownCl[tid]) pc = 0x80000000u | (ccidl[tid] << 8) | myCntC | ((sCkey[tid] >> 12) << 16);
        packR[tid] = pr; packC[tid] = pc;
    }
    __syncthreads();
    if (tid == 0) {
        hdr[1] = (m > 0) ? (rridl[m - 1] + 1u) : 0u;   // nr
        hdr[2] = (m > 0) ? (ccidl[m - 1] + 1u) : 0u;   // nc
    }
    usm[tid] = 1.0f; vsm[tid] = 1.0f;
    __syncthreads();
    if (wv != 0) return;   // waves 1-3 exit (no barriers past here)

    // ---------- D: wave-0 Sinkhorn ----------
    const int nr = (int)hdr[1], nc = (int)hdr[2];
    const unsigned int mxCC = hdr[3];
    float evRr[4], evCr[4], vO[4];
    unsigned int vIx[4], uIx[4], pR[4], pC[4];
    #pragma unroll
    for (int t = 0; t < 4; ++t) {
        int p = lane + (t << 6);
        bool vp = (p < m);
        evRr[t] = vp ? sRval[p] : 0.0f;
        evCr[t] = vp ? sCval[p] : 0.0f;
        vIx[t]  = vp ? vidxl[p] : 0u;
        uIx[t]  = vp ? uidxl[p] : 0u;
        pR[t]   = vp ? packR[p] : 0u;
        pC[t]   = vp ? packC[p] : 0u;
        vO[t] = 1.0f;
    }
    bool r2l = false;
    #pragma unroll
    for (int t = 0; t < 4; ++t) if ((pR[t] >> 31) && (pR[t] & 255u) > 8u) r2l = true;
    const bool r2 = (__ballot(r2l) != 0ull);
    const bool c2 = (mxCC > 8u), c3 = (mxCC > 32u);
    const float bgcF = (float)(B - nc), bgrF = (float)(B - nr);
    float u0 = 1.0f, v0 = 1.0f;
    lgkm0();

    for (int it = 0; it < 30; ++it) {
        // ---- u phase ----
        float pv = 0.0f;
        #pragma unroll
        for (int t = 0; t < 4; ++t) pv += (pC[t] >> 31) ? vO[t] : 0.0f;
        pv = wsum64(pv);
        const float bgu = FLOORK * (bgcF * v0 + pv) + 1e-8f;
        const float u0n = AMASS * rcpf_(bgu);

        #pragma unroll
        for (int t = 0; t < 4; ++t)
            prod[lane + (t << 6)] = evRr[t] * vsm[vIx[t]];
        lgkm0();

        float uO[4];
        #pragma unroll
        for (int t = 0; t < 4; ++t) {
            float ss = 0.0f;
            int base = lane + (t << 6);
            unsigned int cnt = (pR[t] >> 31) ? (pR[t] & 255u) : 0u;
            #pragma unroll
            for (int k = 0; k < 8; ++k)
                if ((unsigned)k < cnt) ss += prod[base + k];
            if (r2) {
                #pragma unroll
                for (int k = 8; k < 32; ++k)
                    if ((unsigned)k < cnt) ss += prod[base + k];
            }
            uO[t] = AMASS * rcpf_(bgu + ss);
        }
        #pragma unroll
        for (int t = 0; t < 4; ++t)
            if (pR[t] >> 31) usm[(pR[t] >> 8) & 255u] = uO[t];

        float pu = 0.0f;
        #pragma unroll
        for (int t = 0; t < 4; ++t) pu += (pR[t] >> 31) ? uO[t] : 0.0f;
        pu = wsum64(pu);
        const float bgv = FLOORK * (bgrF * u0n + pu) + 1e-8f;
        const float v0n = AMASS * rcpf_(bgv);
        lgkm0();

        // ---- v phase ----
        #pragma unroll
        for (int t = 0; t < 4; ++t)
            qarr[lane + (t << 6)] = evCr[t] * usm[uIx[t]];
        lgkm0();

        bool moved = false;
        #pragma unroll
        for (int t = 0; t < 4; ++t) {
            float ss = 0.0f;
            int base = lane + (t << 6);
            unsigned int cnt = (pC[t] >> 31) ? (pC[t] & 255u) : 0u;
            #pragma unroll
            for (int k = 0; k < 8; ++k)
                if ((unsigned)k < cnt) ss += qarr[base + k];
            if (c2) {
                #pragma unroll
                for (int k = 8; k < 32; ++k)
                    if ((unsigned)k < cnt) ss += qarr[base + k];
            }
            if (c3) {
                #pragma unroll
                for (int k = 32; k < 64; ++k)
                    if ((unsigned)k < cnt) ss += qarr[base + k];
            }
            float vn = AMASS * rcpf_(bgv + ss);
            if (pC[t] >> 31) {
                if (fabsf(vn - vO[t]) > EPS_C * vO[t]) moved = true;
                vO[t] = vn;
            }
        }
        #pragma unroll
        for (int t = 0; t < 4; ++t)
            if (pC[t] >> 31) vsm[(pC[t] >> 8) & 255u] = vO[t];

        const bool conv = (__ballot(moved) == 0ull) &&
                          (fabsf(v0n - v0) <= EPS_C * v0) &&
                          (fabsf(u0n - u0) <= EPS_C * u0);
        u0 = u0n; v0 = v0n;
        lgkm0();
        if (conv) break;   // fixed point reached (bounded drift << threshold)
    }

    // epilogue: fill v0, then scatter active columns
    float4* vo4 = (float4*)vout;
    const float4 fill = make_float4(v0, v0, v0, v0);
    #pragma unroll
    for (int t = 0; t < 16; ++t)
        vo4[lane + (t << 6)] = fill;
    vm0();
    #pragma unroll
    for (int t = 0; t < 4; ++t)
        if (pC[t] >> 31) vout[(pC[t] >> 16) & 4095u] = vO[t];
}

// ---------------------------------------------------------------------------
// k4_fb: global-memory dense Sinkhorn fallback (meta[0]==1 only; never for
// this data). Tiny LDS. Correctness-only path.
// ---------------------------------------------------------------------------
__global__ __launch_bounds__(256) void k4_fb(const unsigned int* __restrict__ meta,
                                             const unsigned int* __restrict__ mcount,
                                             const unsigned int* __restrict__ lij,
                                             const float* __restrict__ lval,
                                             float* __restrict__ gv,
                                             float* __restrict__ ga,
                                             float* __restrict__ gb,
                                             float* __restrict__ vout) {
    if (meta[0] == 0u) return;
    __shared__ float red[4];
    __shared__ float bc;
    const int tid = threadIdx.x, lane = tid & 63, wv = tid >> 6;
    const int m = (int)mcount[0];

    for (int i = tid; i < B; i += 256) gv[i] = 1.0f;
    __syncthreads();

    for (int it = 0; it < 30; ++it) {
        float s = 0.0f;
        for (int i = tid; i < B; i += 256) { s += gv[i]; ga[i] = 0.0f; }
        for (int o = 1; o < 64; o <<= 1) s += __shfl_xor(s, o);
        if (lane == 0) red[wv] = s;
        __syncthreads();
        if (tid == 0) bc = red[0] + red[1] + red[2] + red[3];
        __syncthreads();
        const float bgu = FLOORK * bc + 1e-8f;
        for (int e = tid; e < m; e += 256) {
            unsigned int ij = lij[e];
            atomicAdd(&ga[ij >> 12], lval[e] * gv[ij & 4095u]);
        }
        __syncthreads();
        float su = 0.0f;
        for (int i = tid; i < B; i += 256) { su += AMASS / (bgu + ga[i]); gb[i] = 0.0f; }
        for (int o = 1; o < 64; o <<= 1) su += __shfl_xor(su, o);
        if (lane == 0) red[wv] = su;
        __syncthreads();
        if (tid == 0) bc = red[0] + red[1] + red[2] + red[3];
        __syncthreads();
        const float bgv = FLOORK * bc + 1e-8f;
        for (int e = tid; e < m; e += 256) {
            unsigned int ij = lij[e];
            atomicAdd(&gb[ij & 4095u], lval[e] * (AMASS / (bgu + ga[ij >> 12])));
        }
        __syncthreads();
        for (int i = tid; i < B; i += 256) gv[i] = AMASS / (bgv + gb[i]);
        __syncthreads();
    }
    for (int i = tid; i < B; i += 256) vout[i] = gv[i];
}

// ---------------------------------------------------------------------------
// k5: per row: weights = K*v (u cancels), synthetic negative, normalize,
// dot with text row. Unchanged.
// ---------------------------------------------------------------------------
__global__ __launch_bounds__(256) void k5_synth(const int* __restrict__ top_idx,
                                                const float* __restrict__ top_z,
                                                const unsigned int* __restrict__ Mkey,
                                                const float* __restrict__ v,
                                                const float* __restrict__ image,
                                                const float* __restrict__ text,
                                                float* __restrict__ synth_sim) {
    __shared__ float sw[TOPK];
    __shared__ int   sj[TOPK];
    __shared__ float red[4];
    __shared__ float bcast;

    const int row = blockIdx.x, tid = threadIdx.x;
    const int wid = tid >> 6, lane = tid & 63;
    const float M = finv(Mkey[0]);

    if (tid < 64) {
        float wt = 0.0f;
        if (tid < TOPK) {
            int j = top_idx[(size_t)row * TOPK + tid];
            float z = top_z[(size_t)row * TOPK + tid];
            float c = fmaxf(M - z, 0.0f);
            float K = fmaxf(expf(-(c / OT_EPS_F)), FLOORK);
            wt = K * v[j];
            sj[tid] = j;
            sw[tid] = wt;
        }
        float s = wt;
        for (int off = 32; off; off >>= 1) s += __shfl_down(s, off);
        if (tid == 0) bcast = fmaxf(s, 1e-8f);
    }
    __syncthreads();
    if (tid < TOPK) sw[tid] = sw[tid] / bcast;
    __syncthreads();

    float s0 = 0.0f, s1 = 0.0f;
    for (int t = 0; t < TOPK; ++t) {
        float wv2 = sw[t];
        const float* img = image + (size_t)sj[t] * D;
        s0 += wv2 * img[tid];
        s1 += wv2 * img[tid + 256];
    }
    float nn = s0 * s0 + s1 * s1;
    for (int off = 32; off; off >>= 1) nn += __shfl_down(nn, off);
    if (lane == 0) red[wid] = nn;
    __syncthreads();
    float norm2 = red[0] + red[1] + red[2] + red[3];
    float den = sqrtf(norm2) + 1e-8f;
    float p = (s0 / den) * text[(size_t)row * D + tid] +
              (s1 / den) * text[(size_t)row * D + tid + 256];
    __syncthreads();
    for (int off = 32; off; off >>= 1) p += __shfl_down(p, off);
    if (lane == 0) red[wid] = p;
    __syncthreads();
    if (tid == 0) synth_sim[row] = red[0] + red[1] + red[2] + red[3];
}

// ---------------------------------------------------------------------------
// k78: median of ratio via radix select, then gate + final combine. Unchanged.
// ---------------------------------------------------------------------------
__global__ __launch_bounds__(256) void k78_final(const float* __restrict__ ratio,
                                                 const float* __restrict__ synth_sim,
                                                 const double* __restrict__ base_acc,
                                                 float* __restrict__ out) {
    __shared__ unsigned int skey[B];
    __shared__ unsigned int histm[4 * 257 + 4];
    __shared__ unsigned int selb, selk;
    __shared__ double rs[4];
    __shared__ float rg[4];

    const int tid = threadIdx.x, wid = tid >> 6, lane = tid & 63;

    #pragma unroll
    for (int t = 0; t < 16; ++t) {
        int c = tid + (t << 8);
        skey[c] = fkey(ratio[c]);
    }
    __syncthreads();

    unsigned int prefix = 0, kneed = 2048;
    for (int r = 0; r < 4; ++r) {
        for (int i = tid; i < 4 * 257 + 4; i += 256) histm[i] = 0;
        __syncthreads();
        const int shift = 24 - 8 * r;
        unsigned int cb = 0xFFFFFFFFu, cc = 0;
        #pragma unroll
        for (int t = 0; t < 16; ++t) {
            unsigned int kx = skey[tid + (t << 8)];
            bool part = (r == 0) || ((kx >> (32 - 8 * r)) == prefix);
            if (part) {
                unsigned int bin = (kx >> shift) & 255u;
                if (bin == cb) ++cc;
                else {
                    if (cc) atomicAdd(&histm[wid * 257 + cb], cc);
                    cb = bin; cc = 1;
                }
            }
        }
        if (cc) atomicAdd(&histm[wid * 257 + cb], cc);
        __syncthreads();
        unsigned int h = histm[tid] + histm[257 + tid] + histm[514 + tid] + histm[771 + tid];
        unsigned int s = h;
        for (int off = 1; off < 64; off <<= 1) {
            unsigned int o = __shfl_down(s, off);
            if (lane + off < 64) s += o;
        }
        if (lane == 0) histm[1028 + wid] = s;
        __syncthreads();
        unsigned int coarse = 0;
        for (int w = wid + 1; w < 4; ++w) coarse += histm[1028 + w];
        unsigned int incl = s + coarse, strict = incl - h;
        if (strict < kneed && kneed <= incl) { selb = (unsigned int)tid; selk = kneed - strict; }
        __syncthreads();
        prefix = (prefix << 8) | selb;
        kneed = selk;
        __syncthreads();
    }
    const unsigned int KA = prefix;
    const unsigned int g = 2048u - kneed;

    unsigned int ec = 0, mb = 0;
    #pragma unroll
    for (int t = 0; t < 16; ++t) {
        unsigned int kx = skey[tid + (t << 8)];
        if (kx == KA) ++ec;
        else if (kx < KA && kx > mb) mb = kx;
    }
    for (int off = 1; off < 64; off <<= 1) {
        ec += __shfl_xor(ec, off);
        unsigned int o = __shfl_xor(mb, off);
        mb = (o > mb) ? o : mb;
    }
    __syncthreads();
    if (lane == 0) { histm[wid] = ec; histm[8 + wid] = mb; }
    __syncthreads();
    unsigned int E  = histm[0] + histm[1] + histm[2] + histm[3];
    unsigned int MB = max(max(histm[8], histm[9]), max(histm[10], histm[11]));
    unsigned int KB = (g + E >= 2049u) ? KA : MB;
    const float scale = 0.5f * (finv(KA) + finv(KB));

    double lsd = 0.0; float gs = 0.0f;
    #pragma unroll
    for (int t = 0; t < 16; ++t) {
        float sl = scale * synth_sim[tid + (t << 8)];
        if (sl > -0.05f) { gs += 1.0f; lsd += (double)softplusf(sl); }
    }
    for (int off = 1; off < 64; off <<= 1) {
        lsd += __shfl_xor(lsd, off);
        gs  += __shfl_xor(gs, off);
    }
    if (lane == 0) { rs[wid] = lsd; rg[wid] = gs; }
    __syncthreads();
    if (tid == 0) {
        double L = rs[0] + rs[1] + rs[2] + rs[3];
        float  G = rg[0] + rg[1] + rg[2] + rg[3];
        double base = base_acc[0] / ((double)B * (double)B);
        double synth = (G > 0.0f) ? (L / ((double)G + 1e-8)) : 0.0;
        out[0] = (float)(base + 0.5 * synth);
    }
}

extern "C" void kernel_launch(void* const* d_in, const int* in_sizes, int n_in,
                              void* d_out, int out_size, void* d_ws, size_t ws_size,
                              hipStream_t stream) {
    const float* logits = (const float*)d_in[0];
    const float* text   = (const float*)d_in[1];
    const float* image  = (const float*)d_in[2];
    const float* bias   = (const float*)d_in[3];

    char* ws = (char*)d_ws;
    double*       base_acc = (double*)(ws + 0);
    unsigned int* mcount   = (unsigned int*)(ws + 8);
    unsigned int* Mkey     = (unsigned int*)(ws + 12);
    unsigned int* meta     = (unsigned int*)(ws + 16);
    unsigned int* flags    = (unsigned int*)(ws + 64);            // 16 KB
    float*        rowsum   = (float*)(ws + 64 + 16384);
    unsigned int* rowmaxk  = (unsigned int*)(rowsum + B);
    float*        v        = (float*)(rowmaxk + B);
    float*        sim      = v + B;
    float*        ratio    = sim + B;
    float*        gv       = ratio + B;
    float*        ga       = gv + B;
    float*        gb       = ga + B;
    int*          top_idx  = (int*)(gb + B);
    float*        top_z    = (float*)(top_idx + (size_t)B * TOPK);
    unsigned int* lij      = (unsigned int*)(top_z + (size_t)B * TOPK);
    float*        lval     = (float*)(lij + (size_t)B * TOPK);

    // zero: header + flags (k1_fallback gating)
    hipMemsetAsync(ws, 0, 64 + 16384, stream);

    k1_row     <<<B / 4, 256, 0, stream>>>(logits, text, image, bias, rowsum, rowmaxk,
                                           top_idx, top_z, ratio, flags);
    k1_fallback<<<B, 256, 0, stream>>>(logits, bias, flags, top_idx, top_z);
    kmid       <<<1, 256, 0, stream>>>(rowsum, rowmaxk, top_z, top_idx, Mkey, base_acc,
                                       mcount, meta, lij, lval, v);
    k4_fb      <<<1, 256, 0, stream>>>(meta, mcount, lij, lval, gv, ga, gb, v);
    k5_synth   <<<B, 256, 0, stream>>>(top_idx, top_z, Mkey, v, image, text, sim);
    k78_final  <<<1, 256, 0, stream>>>(ratio, sim, base_acc, (float*)d_out);
}

// Round 12
// 178.475 us; speedup vs baseline: 4.0316x; 4.0316x over previous
//
#include <hip/hip_runtime.h>
#include <math.h>

#define B 4096
#define D 512
#define TOPK 32
#define MCAP 2048

constexpr float OT_EPS_F = 0.05f;
constexpr float FLOORK   = 1e-12f;
constexpr float AMASS    = 1.0f / 4096.0f;   // exact 2^-12
constexpr float TAU      = 1.8f;             // k1 candidate prefilter threshold
constexpr float EPS_C    = 3.814697e-6f;     // 2^-18 convergence tolerance
constexpr float CPRE     = 1.45f;            // cost prefilter: e>1e-12 needs c<1.3816

__device__ __forceinline__ float softplusf(float x) {
    return fmaxf(x, 0.0f) + log1pf(expf(-fabsf(x)));
}
__device__ __forceinline__ unsigned int fkey(float f) {
    unsigned int x = __float_as_uint(f);
    return x ^ ((x & 0x80000000u) ? 0xFFFFFFFFu : 0x80000000u);
}
__device__ __forceinline__ float finv(unsigned int k) {
    unsigned int x = (k & 0x80000000u) ? (k ^ 0x80000000u) : ~k;
    return __uint_as_float(x);
}
__device__ __forceinline__ float rcpf_(float x) { return __builtin_amdgcn_rcpf(x); }
__device__ __forceinline__ void lgkm0() {
    asm volatile("s_waitcnt lgkmcnt(0)" ::: "memory");
    __builtin_amdgcn_sched_barrier(0);
}
__device__ __forceinline__ void vm0() {
    asm volatile("s_waitcnt vmcnt(0)" ::: "memory");
}
#define DPPADD(x, ctrl) ((x) + __int_as_float(__builtin_amdgcn_update_dpp(0, __float_as_int(x), (ctrl), 0xf, 0xf, false)))
__device__ __forceinline__ float wsum64(float x) {
    x = DPPADD(x, 0x111);
    x = DPPADD(x, 0x112);
    x = DPPADD(x, 0x114);
    x = DPPADD(x, 0x118);
    x = DPPADD(x, 0x142);
    x = DPPADD(x, 0x143);
    return __int_as_float(__builtin_amdgcn_readlane(__float_as_int(x), 63));
}

// ---------------------------------------------------------------------------
// k1: wave-per-row (4 rows / 256-block). Ballot-based exact top-32 +
// base-loss partial + row max + fused ratio sample. Unchanged.
// ---------------------------------------------------------------------------
__global__ __launch_bounds__(256) void k1_row(const float* __restrict__ logits,
                                              const float* __restrict__ text,
                                              const float* __restrict__ image,
                                              const float* __restrict__ bias_p,
                                              float* __restrict__ rowsum,
                                              unsigned int* __restrict__ rowmaxk,
                                              int* __restrict__ top_idx,
                                              float* __restrict__ top_z,
                                              float* __restrict__ ratio,
                                              unsigned int* __restrict__ flags) {
    __shared__ unsigned int candk[4][128];
    __shared__ unsigned int candi[4][128];
    __shared__ unsigned int wcnt[4];

    const int tid = threadIdx.x, w = tid >> 6, lane = tid & 63;
    const int row = (blockIdx.x << 2) + w;
    const float bias = bias_p[0];
    const float* lr = logits + (size_t)row * B;
    const float4* lr4 = (const float4*)lr;

    if (lane == 0) wcnt[w] = 0;
    candk[w][lane] = 0; candk[w][lane + 64] = 0;

    float lsum = 0.0f, lmax = -INFINITY;
    bool ovf = false;

#define K1ELEM(ZV, CC) do {                                                   \
        float z_ = (ZV) + bias;                                               \
        bool dg_ = ((CC) == row);                                             \
        lsum += dg_ ? softplusf(-z_) : softplusf(z_);                         \
        float zm_ = dg_ ? -INFINITY : z_;                                     \
        lmax = fmaxf(lmax, zm_);                                              \
        if (zm_ > TAU) {                                                      \
            unsigned int p_ = atomicAdd(&wcnt[w], 1u);                        \
            if (p_ < 128u) { candk[w][p_] = fkey(zm_);                        \
                             candi[w][p_] = (unsigned int)(CC); }             \
            else ovf = true;                                                  \
        } } while (0)

    #pragma unroll
    for (int t = 0; t < 16; ++t) {
        float4 z4 = lr4[lane + (t << 6)];
        int cb = (lane << 2) + (t << 8);
        K1ELEM(z4.x, cb);
        K1ELEM(z4.y, cb + 1);
        K1ELEM(z4.z, cb + 2);
        K1ELEM(z4.w, cb + 3);
    }
#undef K1ELEM
    __syncthreads();

    for (int o = 1; o < 64; o <<= 1) {
        lsum += __shfl_xor(lsum, o);
        lmax = fmaxf(lmax, __shfl_xor(lmax, o));
    }
    if (lane == 0) { rowsum[row] = lsum; rowmaxk[row] = fkey(lmax); }

    const unsigned int n = wcnt[w];
    bool fb = (n < (unsigned)TOPK) || (n > 128u) || (__ballot(ovf) != 0ull);

    const unsigned int c0k = candk[w][lane], c1k = candk[w][lane + 64];
    const unsigned int i0  = candi[w][lane], i1  = candi[w][lane + 64];

    if (!fb) {
        unsigned int K = 0u;
        for (int b = 31; b >= 0; --b) {
            unsigned int tr = K | (1u << b);
            int cnt = __popcll(__ballot(c0k >= tr)) + __popcll(__ballot(c1k >= tr));
            if (cnt >= TOPK) K = tr;
        }
        unsigned long long m0g = __ballot(c0k > K), m1g = __ballot(c1k > K);
        unsigned long long m0e = __ballot(c0k == K), m1e = __ballot(c1k == K);
        int cnt_gt = __popcll(m0g) + __popcll(m1g);
        int kneed  = TOPK - cnt_gt;
        int eqc    = __popcll(m0e) + __popcll(m1e);
        if (eqc != kneed) {
            fb = true;
        } else {
            unsigned long long lmlt = (1ull << lane) - 1ull;
            size_t rb = (size_t)row * TOPK;
            int r0 = __popcll(m0g & lmlt);
            if (c0k > K) { top_idx[rb + r0] = (int)i0; top_z[rb + r0] = finv(c0k); }
            int r1 = __popcll(m0g) + __popcll(m1g & lmlt);
            if (c1k > K) { top_idx[rb + r1] = (int)i1; top_z[rb + r1] = finv(c1k); }
            int e0 = cnt_gt + __popcll(m0e & lmlt);
            if (c0k == K) { top_idx[rb + e0] = (int)i0; top_z[rb + e0] = finv(c0k); }
            int e1 = cnt_gt + __popcll(m0e) + __popcll(m1e & lmlt);
            if (c1k == K) { top_idx[rb + e1] = (int)i1; top_z[rb + e1] = finv(c1k); }
        }
    }
    if (fb && lane == 0) flags[row] = 1u;

    // ---- fused ratio sample ----
    unsigned int hh = (unsigned int)row * 2654435761u;
    int j = (int)(((unsigned int)row + 1u + (hh % 4095u)) & 4095u);   // j != row
    const float4* tr4 = (const float4*)(text + (size_t)row * D);
    const float4* ir4 = (const float4*)(image + (size_t)j * D);
    float4 a0 = tr4[lane], b0 = ir4[lane];
    float4 a1 = tr4[lane + 64], b1 = ir4[lane + 64];
    float s3 = a0.x * b0.x + a0.y * b0.y + a0.z * b0.z + a0.w * b0.w
             + a1.x * b1.x + a1.y * b1.y + a1.z * b1.z + a1.w * b1.w;
    for (int o = 1; o < 64; o <<= 1) s3 += __shfl_xor(s3, o);
    if (lane == 0) ratio[row] = lr[j] / (s3 + 1e-8f);
}

// ---------------------------------------------------------------------------
// k1f: exact fallback for flagged rows (LDS radix select). Normally no-op.
// ---------------------------------------------------------------------------
__global__ __launch_bounds__(256) void k1_fallback(const float* __restrict__ logits,
                                                   const float* __restrict__ bias_p,
                                                   const unsigned int* __restrict__ flags,
                                                   int* __restrict__ top_idx,
                                                   float* __restrict__ top_z) {
    const int row = blockIdx.x;
    if (flags[row] == 0u) return;

    __shared__ unsigned int skey[B];
    __shared__ unsigned int histm[4 * 257 + 4];
    __shared__ unsigned int selb, selk;
    __shared__ int cnt_gt, cnt_eq;
    __shared__ int eqi[64];

    const int tid = threadIdx.x, wid = tid >> 6, lane = tid & 63;
    const float bias = bias_p[0];
    const float* lr = logits + (size_t)row * B;

    #pragma unroll
    for (int t = 0; t < 16; ++t) {
        int c = tid + (t << 8);
        float z = lr[c] + bias;
        skey[c] = fkey((c == row) ? -INFINITY : z);
    }
    if (tid == 0) { cnt_gt = 0; cnt_eq = 0; }
    __syncthreads();

    unsigned int prefix = 0, kneed = TOPK;
    for (int r = 0; r < 4; ++r) {
        for (int i = tid; i < 4 * 257 + 4; i += 256) histm[i] = 0;
        __syncthreads();
        const int shift = 24 - 8 * r;
        #pragma unroll
        for (int t = 0; t < 16; ++t) {
            int c = tid + (t << 8);
            unsigned int kx = skey[c];
            bool part = (r == 0) || ((kx >> (32 - 8 * r)) == prefix);
            if (part) atomicAdd(&histm[wid * 257 + ((kx >> shift) & 255u)], 1u);
        }
        __syncthreads();
        unsigned int h = histm[tid] + histm[257 + tid] + histm[514 + tid] + histm[771 + tid];
        unsigned int s = h;
        for (int off = 1; off < 64; off <<= 1) {
            unsigned int o = __shfl_down(s, off);
            if (lane + off < 64) s += o;
        }
        if (lane == 0) histm[1028 + wid] = s;
        __syncthreads();
        unsigned int coarse = 0;
        for (int ww = wid + 1; ww < 4; ++ww) coarse += histm[1028 + ww];
        unsigned int incl = s + coarse, strict = incl - h;
        if (strict < kneed && kneed <= incl) { selb = (unsigned int)tid; selk = kneed - strict; }
        __syncthreads();
        prefix = (prefix << 8) | selb;
        kneed = selk;
        __syncthreads();
    }
    const unsigned int K32 = prefix;

    #pragma unroll
    for (int t = 0; t < 16; ++t) {
        int c = tid + (t << 8);
        unsigned int kx = skey[c];
        if (kx > K32) {
            int p = atomicAdd(&cnt_gt, 1);
            top_idx[(size_t)row * TOPK + p] = c;
            top_z [(size_t)row * TOPK + p] = finv(kx);
        } else if (kx == K32) {
            int p = atomicAdd(&cnt_eq, 1);
            if (p < 64) eqi[p] = c;
        }
    }
    __syncthreads();
    if (tid == 0) {
        int q = (int)kneed, base = cnt_gt, E = cnt_eq;
        float zv = finv(K32);
        if (E <= 64) {
            for (int s2 = 0; s2 < q; ++s2) {
                int best = 0x7FFFFFFF, bp = 0;
                for (int e = 0; e < E; ++e) { int ix = eqi[e]; if (ix < best) { best = ix; bp = e; } }
                eqi[bp] = 0x7FFFFFFF;
                top_idx[(size_t)row * TOPK + base + s2] = best;
                top_z [(size_t)row * TOPK + base + s2] = zv;
            }
        } else {
            int taken = 0;
            for (int c = 0; c < B && taken < q; ++c)
                if (skey[c] == K32) {
                    top_idx[(size_t)row * TOPK + base + taken] = c;
                    top_z [(size_t)row * TOPK + base + taken] = zv;
                    ++taken;
                }
        }
    }
}

// ---------------------------------------------------------------------------
// kmid: fused reduce + CSR build + single-wave Sinkhorn. Capacity m <= 2048.
// Survivors per row are a PREFIX of the descending top-32 => row-CSR free.
// Col-CSR via LDS histogram + scan + scatter (build phase only; loop has
// zero atomics, zero barriers). ~92 KB LDS.
// ---------------------------------------------------------------------------
__global__ __launch_bounds__(256) void kmid(const float* __restrict__ rowsum,
                                            const unsigned int* __restrict__ rowmaxk,
                                            const float* __restrict__ top_z,
                                            const int* __restrict__ top_idx,
                                            unsigned int* __restrict__ Mkey_g,
                                            double* __restrict__ base_acc_g,
                                            unsigned int* __restrict__ mcount_g,
                                            unsigned int* __restrict__ meta_g,
                                            float* __restrict__ vout) {
    __shared__ __align__(16) unsigned char SB[94208];
    float*  rcsr_val = (float*)(SB + 0);                    // [2048] 8KB
    float*  ccsr_val = (float*)(SB + 8192);                 // [2048] 8KB
    float*  arr      = (float*)(SB + 16384);                // [2048] 8KB (prod/q shared)
    float*  usm      = (float*)(SB + 24576);                // [2048] 8KB
    float*  vsm      = (float*)(SB + 32768);                // [2048] 8KB
    unsigned* aRowSC = (unsigned*)(SB + 40960);             // [2048] 8KB (start|cnt<<16)
    unsigned* aColSC = (unsigned*)(SB + 49152);             // [2048] 8KB
    unsigned short* rcsr_cid = (unsigned short*)(SB + 57344); // [2048] 4KB
    unsigned short* ccsr_rid = (unsigned short*)(SB + 61440); // [2048] 4KB
    unsigned short* aColJ    = (unsigned short*)(SB + 65536); // [2048] 4KB
    unsigned* colPS  = (unsigned*)(SB + 69632);             // [4096] 16KB (ptr|comp<<16)
    unsigned short* rowCnt = (unsigned short*)(SB + 86016); // [4096] 8KB
    // overlays (build only):
    unsigned* colCnt  = (unsigned*)(SB + 0);                // [4096] 16KB over rcsr/ccsr_val
    unsigned* rowPS   = (unsigned*)(SB + 24576);            // [4096] 16KB over usm/vsm
    unsigned* colFill = (unsigned*)(SB + 16384);            // [2048] 8KB over arr (2 cols/u32)

    __shared__ double sdbl[4];
    __shared__ unsigned smax4[4];
    __shared__ float sMf;
    __shared__ unsigned mTot;
    __shared__ unsigned wq[4];
    __shared__ unsigned nrS, ncS;

    const int tid = threadIdx.x, lane = tid & 63, wv = tid >> 6;

    // ---------- A: reduce rowsum/rowmaxk ----------
    {
        double s = 0.0; unsigned mk = 0u;
        #pragma unroll
        for (int t = 0; t < 16; ++t) {
            int i = tid + (t << 8);
            s += (double)rowsum[i];
            unsigned k = rowmaxk[i];
            mk = (k > mk) ? k : mk;
        }
        for (int o = 1; o < 64; o <<= 1) {
            s += __shfl_xor(s, o);
            unsigned om = __shfl_xor(mk, o);
            mk = (om > mk) ? om : mk;
        }
        if (lane == 0) { sdbl[wv] = s; smax4[wv] = mk; }
        if (tid == 0) mTot = 0u;
    }
    __syncthreads();
    if (tid == 0) {
        *base_acc_g = sdbl[0] + sdbl[1] + sdbl[2] + sdbl[3];
        unsigned m2 = max(max(smax4[0], smax4[1]), max(smax4[2], smax4[3]));
        *Mkey_g = m2;
        sMf = finv(m2);
    }
    __syncthreads();
    const float M = sMf;

    // ---------- B1: count survivors (prefix property) + col histogram ----------
    for (int i = tid; i < 4096; i += 256) colCnt[i] = 0u;
    __syncthreads();
    {
        unsigned myTot = 0;
        for (int i = 0; i < 16; ++i) {
            int r = tid * 16 + i;
            const float* tz = top_z + (size_t)r * TOPK;
            const int* tj = top_idx + (size_t)r * TOPK;
            int cnt = 0;
            for (int k = 0; k < TOPK; ++k) {
                float c = fmaxf(M - tz[k], 0.0f);
                if (c >= CPRE) break;
                float e = expf(-(c / OT_EPS_F));
                if (!(e > FLOORK)) break;
                ++cnt;
                atomicAdd(&colCnt[(unsigned)tj[k]], 1u);
            }
            rowCnt[r] = (unsigned short)cnt;
            myTot += (unsigned)cnt;
        }
        atomicAdd(&mTot, myTot);
    }
    __syncthreads();
    const int m = (int)mTot;
    if (tid == 0) { mcount_g[0] = (unsigned)m; meta_g[0] = (m > MCAP) ? 1u : 0u; }
    if (m > MCAP) return;

    // ---------- B2a: row scan -> rowPS (ptr|comp<<16) + aRowSC ----------
    {
        unsigned pre[16]; unsigned tsum = 0;
        #pragma unroll
        for (int i = 0; i < 16; ++i) {
            unsigned c2 = rowCnt[tid * 16 + i];
            unsigned val = c2 | ((c2 ? 1u : 0u) << 16);
            pre[i] = tsum; tsum += val;
        }
        unsigned sc = tsum;
        for (int o = 1; o < 64; o <<= 1) {
            unsigned n2 = __shfl_up(sc, o);
            if (lane >= o) sc += n2;
        }
        if (lane == 63) wq[wv] = sc;
        __syncthreads();
        unsigned woff = 0;
        for (int w2 = 0; w2 < wv; ++w2) woff += wq[w2];
        unsigned base0 = woff + sc - tsum;
        #pragma unroll
        for (int i = 0; i < 16; ++i) {
            int r = tid * 16 + i;
            unsigned pfx = base0 + pre[i];
            rowPS[r] = pfx;
            unsigned c2 = rowCnt[r];
            if (c2) aRowSC[pfx >> 16] = (pfx & 0xFFFFu) | (c2 << 16);
        }
        if (tid == 255) nrS = (base0 + tsum) >> 16;
    }
    __syncthreads();
    // ---------- B2b: col scan -> colPS + aColSC + aColJ ----------
    {
        unsigned pre[16]; unsigned tsum = 0;
        #pragma unroll
        for (int i = 0; i < 16; ++i) {
            unsigned c2 = colCnt[tid * 16 + i];
            unsigned val = c2 | ((c2 ? 1u : 0u) << 16);
            pre[i] = tsum; tsum += val;
        }
        unsigned sc = tsum;
        for (int o = 1; o < 64; o <<= 1) {
            unsigned n2 = __shfl_up(sc, o);
            if (lane >= o) sc += n2;
        }
        if (lane == 63) wq[wv] = sc;
        __syncthreads();   // also: colCnt fully read by all threads after this point? reads happened above ✓
        unsigned woff = 0;
        for (int w2 = 0; w2 < wv; ++w2) woff += wq[w2];
        unsigned base0 = woff + sc - tsum;
        #pragma unroll
        for (int i = 0; i < 16; ++i) {
            int j = tid * 16 + i;
            unsigned pfx = base0 + pre[i];
            colPS[j] = pfx;
            unsigned c2 = colCnt[j];
            if (c2) {
                unsigned cc = pfx >> 16;
                aColSC[cc] = (pfx & 0xFFFFu) | (c2 << 16);
                aColJ[cc] = (unsigned short)j;
            }
        }
        if (tid == 255) ncS = (base0 + tsum) >> 16;
    }
    __syncthreads();
    // ---------- B3: fill CSR (colFill: two 16-bit counters per u32) ----------
    for (int i = tid; i < 2048; i += 256) colFill[i] = 0u;
    __syncthreads();
    for (int i = 0; i < 16; ++i) {
        int r = tid * 16 + i;
        int cnt = rowCnt[r];
        if (!cnt) continue;
        unsigned rps = rowPS[r];
        unsigned rptr = rps & 0xFFFFu, rcomp = rps >> 16;
        const float* tz = top_z + (size_t)r * TOPK;
        const int* tj = top_idx + (size_t)r * TOPK;
        for (int k = 0; k < cnt; ++k) {
            float c = fmaxf(M - tz[k], 0.0f);
            float e = expf(-(c / OT_EPS_F));
            float wv2 = e - FLOORK;
            unsigned pos = rptr + (unsigned)k;
            unsigned j = (unsigned)tj[k];
            unsigned cps = colPS[j];
            rcsr_val[pos] = wv2;
            rcsr_cid[pos] = (unsigned short)(cps >> 16);
            unsigned inc = (j & 1u) ? 65536u : 1u;
            unsigned old = atomicAdd(&colFill[j >> 1], inc);
            unsigned prior = (old >> ((j & 1u) * 16u)) & 0xFFFFu;
            unsigned cpos = (cps & 0xFFFFu) + prior;
            ccsr_val[cpos] = wv2;
            ccsr_rid[cpos] = (unsigned short)rcomp;
        }
    }
    __syncthreads();
    // ---------- B4: init scaling tables (frees rowPS alias) ----------
    for (int i = tid; i < 2048; i += 256) { usm[i] = 1.0f; vsm[i] = 1.0f; }
    __syncthreads();
    if (wv != 0) return;   // single-wave loop; no barriers past here

    // ---------- D: Sinkhorn ----------
    const int nr = (int)nrS, nc = (int)ncS;
    float u0 = 1.0f, v0 = 1.0f;
    float SvA = (float)nc;
    for (int it = 0; it < 30; ++it) {
        const float bgu = FLOORK * ((float)(B - nc) * v0 + SvA) + 1e-8f;
        const float u0n = AMASS * rcpf_(bgu);
        for (int e = lane; e < m; e += 64)
            arr[e] = rcsr_val[e] * vsm[rcsr_cid[e]];
        lgkm0();
        float SuP = 0.0f;
        for (int i = lane; i < nr; i += 64) {
            unsigned sc = aRowSC[i];
            unsigned st = sc & 0xFFFFu, ct = sc >> 16;
            float ss = 0.0f;
            #pragma unroll
            for (unsigned k = 0; k < 8; ++k)
                if (k < ct) ss += arr[st + k];
            if (ct > 8u)
                for (unsigned k = 8; k < ct; ++k) ss += arr[st + k];
            float u = AMASS * rcpf_(bgu + ss);
            usm[i] = u; SuP += u;
        }
        const float Su = wsum64(SuP);
        const float bgv = FLOORK * ((float)(B - nr) * u0n + Su) + 1e-8f;
        const float v0n = AMASS * rcpf_(bgv);
        lgkm0();
        for (int e = lane; e < m; e += 64)
            arr[e] = ccsr_val[e] * usm[ccsr_rid[e]];
        lgkm0();
        float SvP = 0.0f; bool moved = false;
        for (int i = lane; i < nc; i += 64) {
            unsigned sc = aColSC[i];
            unsigned st = sc & 0xFFFFu, ct = sc >> 16;
            float ss = 0.0f;
            #pragma unroll
            for (unsigned k = 0; k < 8; ++k)
                if (k < ct) ss += arr[st + k];
            if (ct > 8u)
                for (unsigned k = 8; k < ct; ++k) ss += arr[st + k];
            float vn = AMASS * rcpf_(bgv + ss);
            float vold = vsm[i];
            if (fabsf(vn - vold) > EPS_C * vold) moved = true;
            vsm[i] = vn; SvP += vn;
        }
        SvA = wsum64(SvP);
        const bool conv = (__ballot(moved) == 0ull) &&
                          (fabsf(v0n - v0) <= EPS_C * v0) &&
                          (fabsf(u0n - u0) <= EPS_C * u0);
        u0 = u0n; v0 = v0n;
        lgkm0();
        if (conv) break;
    }
    // epilogue: fill background v0, overwrite active cols
    float4* vo4 = (float4*)vout;
    const float4 fill = make_float4(v0, v0, v0, v0);
    #pragma unroll
    for (int t = 0; t < 16; ++t)
        vo4[lane + (t << 6)] = fill;
    vm0();
    for (int i = lane; i < nc; i += 64)
        vout[aColJ[i]] = vsm[i];
}

// ---------------------------------------------------------------------------
// kdiag: duration encodes m (dur_us ~= m * 0.027). Diagnostic only.
// ---------------------------------------------------------------------------
__global__ __launch_bounds__(64) void kdiag(const unsigned int* __restrict__ mcount) {
    if (threadIdx.x == 0) {
        int m = (int)mcount[0];
        if (m > 4096) m = 4096;
        for (int i = 0; i < m; ++i) __builtin_amdgcn_s_sleep(1);
    }
}

// ---------------------------------------------------------------------------
// k4_fb: list-free dense-ish global Sinkhorn fallback (m > MCAP only).
// Recomputes per-slot kernel values once into evals, then 30 iterations with
// global atomics. Correctness-only path.
// ---------------------------------------------------------------------------
__global__ __launch_bounds__(256) void k4_fb(const unsigned int* __restrict__ meta,
                                             const unsigned int* __restrict__ Mkey,
                                             const float* __restrict__ top_z,
                                             const int* __restrict__ top_idx,
                                             float* __restrict__ evals,
                                             float* __restrict__ gv,
                                             float* __restrict__ ga,
                                             float* __restrict__ gb,
                                             float* __restrict__ vout) {
    if (meta[0] == 0u) return;
    __shared__ float red[4];
    __shared__ float bc;
    const int tid = threadIdx.x, lane = tid & 63, wv = tid >> 6;
    const float M = finv(Mkey[0]);

    for (int c = tid; c < B * TOPK; c += 256) {
        float cc = fmaxf(M - top_z[c], 0.0f);
        float e = 0.0f;
        if (cc < CPRE) {
            float t = expf(-(cc / OT_EPS_F));
            if (t > FLOORK) e = t - FLOORK;
        }
        evals[c] = e;
    }
    for (int i = tid; i < B; i += 256) gv[i] = 1.0f;
    __syncthreads();

    for (int it = 0; it < 30; ++it) {
        float s = 0.0f;
        for (int i = tid; i < B; i += 256) { s += gv[i]; ga[i] = 0.0f; }
        for (int o = 1; o < 64; o <<= 1) s += __shfl_xor(s, o);
        if (lane == 0) red[wv] = s;
        __syncthreads();
        if (tid == 0) bc = red[0] + red[1] + red[2] + red[3];
        __syncthreads();
        const float bgu = FLOORK * bc + 1e-8f;
        for (int c = tid; c < B * TOPK; c += 256) {
            float a = evals[c];
            if (a > 0.0f) atomicAdd(&ga[c >> 5], a * gv[top_idx[c]]);
        }
        __syncthreads();
        float su = 0.0f;
        for (int i = tid; i < B; i += 256) { su += AMASS / (bgu + ga[i]); gb[i] = 0.0f; }
        for (int o = 1; o < 64; o <<= 1) su += __shfl_xor(su, o);
        if (lane == 0) red[wv] = su;
        __syncthreads();
        if (tid == 0) bc = red[0] + red[1] + red[2] + red[3];
        __syncthreads();
        const float bgv = FLOORK * bc + 1e-8f;
        for (int c = tid; c < B * TOPK; c += 256) {
            float a = evals[c];
            if (a > 0.0f) {
                float u = AMASS / (bgu + ga[c >> 5]);
                atomicAdd(&gb[top_idx[c]], a * u);
            }
        }
        __syncthreads();
        for (int i = tid; i < B; i += 256) gv[i] = AMASS / (bgv + gb[i]);
        __syncthreads();
    }
    for (int i = tid; i < B; i += 256) vout[i] = gv[i];
}

// ---------------------------------------------------------------------------
// k5: per row: weights = K*v (u cancels), synthetic negative, normalize,
// dot with text row. Unchanged.
// ---------------------------------------------------------------------------
__global__ __launch_bounds__(256) void k5_synth(const int* __restrict__ top_idx,
                                                const float* __restrict__ top_z,
                                                const unsigned int* __restrict__ Mkey,
                                                const float* __restrict__ v,
                                                const float* __restrict__ image,
                                                const float* __restrict__ text,
                                                float* __restrict__ synth_sim) {
    __shared__ float sw[TOPK];
    __shared__ int   sj[TOPK];
    __shared__ float red[4];
    __shared__ float bcast;

    const int row = blockIdx.x, tid = threadIdx.x;
    const int wid = tid >> 6, lane = tid & 63;
    const float M = finv(Mkey[0]);

    if (tid < 64) {
        float wt = 0.0f;
        if (tid < TOPK) {
            int j = top_idx[(size_t)row * TOPK + tid];
            float z = top_z[(size_t)row * TOPK + tid];
            float c = fmaxf(M - z, 0.0f);
            float K = fmaxf(expf(-(c / OT_EPS_F)), FLOORK);
            wt = K * v[j];
            sj[tid] = j;
            sw[tid] = wt;
        }
        float s = wt;
        for (int off = 32; off; off >>= 1) s += __shfl_down(s, off);
        if (tid == 0) bcast = fmaxf(s, 1e-8f);
    }
    __syncthreads();
    if (tid < TOPK) sw[tid] = sw[tid] / bcast;
    __syncthreads();

    float s0 = 0.0f, s1 = 0.0f;
    for (int t = 0; t < TOPK; ++t) {
        float wv2 = sw[t];
        const float* img = image + (size_t)sj[t] * D;
        s0 += wv2 * img[tid];
        s1 += wv2 * img[tid + 256];
    }
    float nn = s0 * s0 + s1 * s1;
    for (int off = 32; off; off >>= 1) nn += __shfl_down(nn, off);
    if (lane == 0) red[wid] = nn;
    __syncthreads();
    float norm2 = red[0] + red[1] + red[2] + red[3];
    float den = sqrtf(norm2) + 1e-8f;
    float p = (s0 / den) * text[(size_t)row * D + tid] +
              (s1 / den) * text[(size_t)row * D + tid + 256];
    __syncthreads();
    for (int off = 32; off; off >>= 1) p += __shfl_down(p, off);
    if (lane == 0) red[wid] = p;
    __syncthreads();
    if (tid == 0) synth_sim[row] = red[0] + red[1] + red[2] + red[3];
}

// ---------------------------------------------------------------------------
// k78: median of ratio via radix select, then gate + final combine. Unchanged.
// ---------------------------------------------------------------------------
__global__ __launch_bounds__(256) void k78_final(const float* __restrict__ ratio,
                                                 const float* __restrict__ synth_sim,
                                                 const double* __restrict__ base_acc,
                                                 float* __restrict__ out) {
    __shared__ unsigned int skey[B];
    __shared__ unsigned int histm[4 * 257 + 4];
    __shared__ unsigned int selb, selk;
    __shared__ double rs[4];
    __shared__ float rg[4];

    const int tid = threadIdx.x, wid = tid >> 6, lane = tid & 63;

    #pragma unroll
    for (int t = 0; t < 16; ++t) {
        int c = tid + (t << 8);
        skey[c] = fkey(ratio[c]);
    }
    __syncthreads();

    unsigned int prefix = 0, kneed = 2048;
    for (int r = 0; r < 4; ++r) {
        for (int i = tid; i < 4 * 257 + 4; i += 256) histm[i] = 0;
        __syncthreads();
        const int shift = 24 - 8 * r;
        unsigned int cb = 0xFFFFFFFFu, cc = 0;
        #pragma unroll
        for (int t = 0; t < 16; ++t) {
            unsigned int kx = skey[tid + (t << 8)];
            bool part = (r == 0) || ((kx >> (32 - 8 * r)) == prefix);
            if (part) {
                unsigned int bin = (kx >> shift) & 255u;
                if (bin == cb) ++cc;
                else {
                    if (cc) atomicAdd(&histm[wid * 257 + cb], cc);
                    cb = bin; cc = 1;
                }
            }
        }
        if (cc) atomicAdd(&histm[wid * 257 + cb], cc);
        __syncthreads();
        unsigned int h = histm[tid] + histm[257 + tid] + histm[514 + tid] + histm[771 + tid];
        unsigned int s = h;
        for (int off = 1; off < 64; off <<= 1) {
            unsigned int o = __shfl_down(s, off);
            if (lane + off < 64) s += o;
        }
        if (lane == 0) histm[1028 + wid] = s;
        __syncthreads();
        unsigned int coarse = 0;
        for (int w = wid + 1; w < 4; ++w) coarse += histm[1028 + w];
        unsigned int incl = s + coarse, strict = incl - h;
        if (strict < kneed && kneed <= incl) { selb = (unsigned int)tid; selk = kneed - strict; }
        __syncthreads();
        prefix = (prefix << 8) | selb;
        kneed = selk;
        __syncthreads();
    }
    const unsigned int KA = prefix;
    const unsigned int g = 2048u - kneed;

    unsigned int ec = 0, mb = 0;
    #pragma unroll
    for (int t = 0; t < 16; ++t) {
        unsigned int kx = skey[tid + (t << 8)];
        if (kx == KA) ++ec;
        else if (kx < KA && kx > mb) mb = kx;
    }
    for (int off = 1; off < 64; off <<= 1) {
        ec += __shfl_xor(ec, off);
        unsigned int o = __shfl_xor(mb, off);
        mb = (o > mb) ? o : mb;
    }
    __syncthreads();
    if (lane == 0) { histm[wid] = ec; histm[8 + wid] = mb; }
    __syncthreads();
    unsigned int E  = histm[0] + histm[1] + histm[2] + histm[3];
    unsigned int MB = max(max(histm[8], histm[9]), max(histm[10], histm[11]));
    unsigned int KB = (g + E >= 2049u) ? KA : MB;
    const float scale = 0.5f * (finv(KA) + finv(KB));

    double lsd = 0.0; float gs = 0.0f;
    #pragma unroll
    for (int t = 0; t < 16; ++t) {
        float sl = scale * synth_sim[tid + (t << 8)];
        if (sl > -0.05f) { gs += 1.0f; lsd += (double)softplusf(sl); }
    }
    for (int off = 1; off < 64; off <<= 1) {
        lsd += __shfl_xor(lsd, off);
        gs  += __shfl_xor(gs, off);
    }
    if (lane == 0) { rs[wid] = lsd; rg[wid] = gs; }
    __syncthreads();
    if (tid == 0) {
        double L = rs[0] + rs[1] + rs[2] + rs[3];
        float  G = rg[0] + rg[1] + rg[2] + rg[3];
        double base = base_acc[0] / ((double)B * (double)B);
        double synth = (G > 0.0f) ? (L / ((double)G + 1e-8)) : 0.0;
        out[0] = (float)(base + 0.5 * synth);
    }
}

extern "C" void kernel_launch(void* const* d_in, const int* in_sizes, int n_in,
                              void* d_out, int out_size, void* d_ws, size_t ws_size,
                              hipStream_t stream) {
    const float* logits = (const float*)d_in[0];
    const float* text   = (const float*)d_in[1];
    const float* image  = (const float*)d_in[2];
    const float* bias   = (const float*)d_in[3];

    char* ws = (char*)d_ws;
    double*       base_acc = (double*)(ws + 0);
    unsigned int* mcount   = (unsigned int*)(ws + 8);
    unsigned int* Mkey     = (unsigned int*)(ws + 12);
    unsigned int* meta     = (unsigned int*)(ws + 16);
    unsigned int* flags    = (unsigned int*)(ws + 64);            // 16 KB
    float*        rowsum   = (float*)(ws + 64 + 16384);
    unsigned int* rowmaxk  = (unsigned int*)(rowsum + B);
    float*        v        = (float*)(rowmaxk + B);
    float*        sim      = v + B;
    float*        ratio    = sim + B;
    float*        gv       = ratio + B;
    float*        ga       = gv + B;
    float*        gb       = ga + B;
    int*          top_idx  = (int*)(gb + B);
    float*        top_z    = (float*)(top_idx + (size_t)B * TOPK);
    float*        evals    = (float*)(top_z + (size_t)B * TOPK);

    // zero: header + flags (k1_fallback gating)
    hipMemsetAsync(ws, 0, 64 + 16384, stream);

    k1_row     <<<B / 4, 256, 0, stream>>>(logits, text, image, bias, rowsum, rowmaxk,
                                           top_idx, top_z, ratio, flags);
    k1_fallback<<<B, 256, 0, stream>>>(logits, bias, flags, top_idx, top_z);
    kmid       <<<1, 256, 0, stream>>>(rowsum, rowmaxk, top_z, top_idx, Mkey, base_acc,
                                       mcount, meta, v);
    kdiag      <<<1, 64, 0, stream>>>(mcount);
    k4_fb      <<<1, 256, 0, stream>>>(meta, Mkey, top_z, top_idx, evals, gv, ga, gb, v);
    k5_synth   <<<B, 256, 0, stream>>>(top_idx, top_z, Mkey, v, image, text, sim);
    k78_final  <<<1, 256, 0, stream>>>(ratio, sim, base_acc, (float*)d_out);
}

// Round 13
// 141.538 us; speedup vs baseline: 5.0837x; 1.2610x over previous
//
#include <hip/hip_runtime.h>
#include <math.h>

#define B 4096
#define D 512
#define TOPK 32
#define MCAP 2048

constexpr float OT_EPS_F = 0.05f;
constexpr float FLOORK   = 1e-12f;
constexpr float AMASS    = 1.0f / 4096.0f;   // exact 2^-12
constexpr float TAU      = 1.8f;             // k1 candidate prefilter threshold
constexpr float EPS_C    = 3.814697e-6f;     // 2^-18 convergence tolerance
constexpr float CPRE     = 1.45f;            // cost prefilter: e>1e-12 needs c<1.3816

// fast softplus via HW transcendentals (v_exp_f32 / v_log_f32), ~1e-7 abs err
__device__ __forceinline__ float softplusf(float x) {
    return fmaxf(x, 0.0f) + __logf(1.0f + __expf(-fabsf(x)));
}
__device__ __forceinline__ unsigned int fkey(float f) {
    unsigned int x = __float_as_uint(f);
    return x ^ ((x & 0x80000000u) ? 0xFFFFFFFFu : 0x80000000u);
}
__device__ __forceinline__ float finv(unsigned int k) {
    unsigned int x = (k & 0x80000000u) ? (k ^ 0x80000000u) : ~k;
    return __uint_as_float(x);
}
__device__ __forceinline__ float rcpf_(float x) { return __builtin_amdgcn_rcpf(x); }
__device__ __forceinline__ void lgkm0() {
    asm volatile("s_waitcnt lgkmcnt(0)" ::: "memory");
    __builtin_amdgcn_sched_barrier(0);
}
__device__ __forceinline__ void vm0() {
    asm volatile("s_waitcnt vmcnt(0)" ::: "memory");
}
#define DPPADD(x, ctrl) ((x) + __int_as_float(__builtin_amdgcn_update_dpp(0, __float_as_int(x), (ctrl), 0xf, 0xf, false)))
__device__ __forceinline__ float wsum64(float x) {
    x = DPPADD(x, 0x111);
    x = DPPADD(x, 0x112);
    x = DPPADD(x, 0x114);
    x = DPPADD(x, 0x118);
    x = DPPADD(x, 0x142);
    x = DPPADD(x, 0x143);
    return __int_as_float(__builtin_amdgcn_readlane(__float_as_int(x), 63));
}

// ---------------------------------------------------------------------------
// k1: wave-per-row (4 rows / 256-block). HW-transcendental softplus,
// raw-positive-float candidate keys (z > TAU > 0 so bit order == float order),
// ballot-based exact top-32, base-loss partial, row max, fused ratio sample.
// ---------------------------------------------------------------------------
__global__ __launch_bounds__(256) void k1_row(const float* __restrict__ logits,
                                              const float* __restrict__ text,
                                              const float* __restrict__ image,
                                              const float* __restrict__ bias_p,
                                              float* __restrict__ rowsum,
                                              unsigned int* __restrict__ rowmaxk,
                                              int* __restrict__ top_idx,
                                              float* __restrict__ top_z,
                                              float* __restrict__ ratio,
                                              unsigned int* __restrict__ flags) {
    __shared__ unsigned int candk[4][128];
    __shared__ unsigned int candi[4][128];
    __shared__ unsigned int wcnt[4];

    const int tid = threadIdx.x, w = tid >> 6, lane = tid & 63;
    const int row = (blockIdx.x << 2) + w;
    const float bias = bias_p[0];
    const float* lr = logits + (size_t)row * B;
    const float4* lr4 = (const float4*)lr;

    if (lane == 0) wcnt[w] = 0;
    candk[w][lane] = 0; candk[w][lane + 64] = 0;

    float lsum = 0.0f, lmax = -INFINITY;
    bool ovf = false;

// softplus(-z) == softplus(z) - z exactly (same fp path in our formula)
#define K1ELEM(ZV, CC) do {                                                   \
        float z_ = (ZV) + bias;                                               \
        bool dg_ = ((CC) == row);                                             \
        float sp_ = softplusf(z_);                                            \
        lsum += dg_ ? (sp_ - z_) : sp_;                                       \
        float zm_ = dg_ ? -INFINITY : z_;                                     \
        lmax = fmaxf(lmax, zm_);                                              \
        if (zm_ > TAU) {                                                      \
            unsigned int p_ = atomicAdd(&wcnt[w], 1u);                        \
            if (p_ < 128u) { candk[w][p_] = __float_as_uint(z_);              \
                             candi[w][p_] = (unsigned int)(CC); }             \
            else ovf = true;                                                  \
        } } while (0)

    #pragma unroll
    for (int t = 0; t < 16; ++t) {
        float4 z4 = lr4[lane + (t << 6)];
        int cb = (lane << 2) + (t << 8);
        K1ELEM(z4.x, cb);
        K1ELEM(z4.y, cb + 1);
        K1ELEM(z4.z, cb + 2);
        K1ELEM(z4.w, cb + 3);
    }
#undef K1ELEM
    __syncthreads();

    for (int o = 1; o < 64; o <<= 1) {
        lsum += __shfl_xor(lsum, o);
        lmax = fmaxf(lmax, __shfl_xor(lmax, o));
    }
    if (lane == 0) { rowsum[row] = lsum; rowmaxk[row] = fkey(lmax); }

    const unsigned int n = wcnt[w];
    bool fb = (n < (unsigned)TOPK) || (n > 128u) || (__ballot(ovf) != 0ull);

    const unsigned int c0k = candk[w][lane], c1k = candk[w][lane + 64];
    const unsigned int i0  = candi[w][lane], i1  = candi[w][lane + 64];

    if (!fb) {
        // ballot binary search for rank-32 key (raw positive-float bits)
        unsigned int K = 0u;
        for (int b = 31; b >= 0; --b) {
            unsigned int tr = K | (1u << b);
            int cnt = __popcll(__ballot(c0k >= tr)) + __popcll(__ballot(c1k >= tr));
            if (cnt >= TOPK) K = tr;
        }
        unsigned long long m0g = __ballot(c0k > K), m1g = __ballot(c1k > K);
        unsigned long long m0e = __ballot(c0k == K), m1e = __ballot(c1k == K);
        int cnt_gt = __popcll(m0g) + __popcll(m1g);
        int kneed  = TOPK - cnt_gt;
        int eqc    = __popcll(m0e) + __popcll(m1e);
        if (eqc != kneed) {
            fb = true;
        } else {
            unsigned long long lmlt = (1ull << lane) - 1ull;
            size_t rb = (size_t)row * TOPK;
            int r0 = __popcll(m0g & lmlt);
            if (c0k > K) { top_idx[rb + r0] = (int)i0; top_z[rb + r0] = __uint_as_float(c0k); }
            int r1 = __popcll(m0g) + __popcll(m1g & lmlt);
            if (c1k > K) { top_idx[rb + r1] = (int)i1; top_z[rb + r1] = __uint_as_float(c1k); }
            int e0 = cnt_gt + __popcll(m0e & lmlt);
            if (c0k == K) { top_idx[rb + e0] = (int)i0; top_z[rb + e0] = __uint_as_float(c0k); }
            int e1 = cnt_gt + __popcll(m0e) + __popcll(m1e & lmlt);
            if (c1k == K) { top_idx[rb + e1] = (int)i1; top_z[rb + e1] = __uint_as_float(c1k); }
        }
    }
    if (fb && lane == 0) flags[row] = 1u;

    // ---- fused ratio sample ----
    unsigned int hh = (unsigned int)row * 2654435761u;
    int j = (int)(((unsigned int)row + 1u + (hh % 4095u)) & 4095u);   // j != row
    const float4* tr4 = (const float4*)(text + (size_t)row * D);
    const float4* ir4 = (const float4*)(image + (size_t)j * D);
    float4 a0 = tr4[lane], b0 = ir4[lane];
    float4 a1 = tr4[lane + 64], b1 = ir4[lane + 64];
    float s3 = a0.x * b0.x + a0.y * b0.y + a0.z * b0.z + a0.w * b0.w
             + a1.x * b1.x + a1.y * b1.y + a1.z * b1.z + a1.w * b1.w;
    for (int o = 1; o < 64; o <<= 1) s3 += __shfl_xor(s3, o);
    if (lane == 0) ratio[row] = lr[j] / (s3 + 1e-8f);
}

// ---------------------------------------------------------------------------
// k1f: exact fallback for flagged rows (LDS radix select). Normally no-op.
// ---------------------------------------------------------------------------
__global__ __launch_bounds__(256) void k1_fallback(const float* __restrict__ logits,
                                                   const float* __restrict__ bias_p,
                                                   const unsigned int* __restrict__ flags,
                                                   int* __restrict__ top_idx,
                                                   float* __restrict__ top_z) {
    const int row = blockIdx.x;
    if (flags[row] == 0u) return;

    __shared__ unsigned int skey[B];
    __shared__ unsigned int histm[4 * 257 + 4];
    __shared__ unsigned int selb, selk;
    __shared__ int cnt_gt, cnt_eq;
    __shared__ int eqi[64];

    const int tid = threadIdx.x, wid = tid >> 6, lane = tid & 63;
    const float bias = bias_p[0];
    const float* lr = logits + (size_t)row * B;

    #pragma unroll
    for (int t = 0; t < 16; ++t) {
        int c = tid + (t << 8);
        float z = lr[c] + bias;
        skey[c] = fkey((c == row) ? -INFINITY : z);
    }
    if (tid == 0) { cnt_gt = 0; cnt_eq = 0; }
    __syncthreads();

    unsigned int prefix = 0, kneed = TOPK;
    for (int r = 0; r < 4; ++r) {
        for (int i = tid; i < 4 * 257 + 4; i += 256) histm[i] = 0;
        __syncthreads();
        const int shift = 24 - 8 * r;
        #pragma unroll
        for (int t = 0; t < 16; ++t) {
            int c = tid + (t << 8);
            unsigned int kx = skey[c];
            bool part = (r == 0) || ((kx >> (32 - 8 * r)) == prefix);
            if (part) atomicAdd(&histm[wid * 257 + ((kx >> shift) & 255u)], 1u);
        }
        __syncthreads();
        unsigned int h = histm[tid] + histm[257 + tid] + histm[514 + tid] + histm[771 + tid];
        unsigned int s = h;
        for (int off = 1; off < 64; off <<= 1) {
            unsigned int o = __shfl_down(s, off);
            if (lane + off < 64) s += o;
        }
        if (lane == 0) histm[1028 + wid] = s;
        __syncthreads();
        unsigned int coarse = 0;
        for (int ww = wid + 1; ww < 4; ++ww) coarse += histm[1028 + ww];
        unsigned int incl = s + coarse, strict = incl - h;
        if (strict < kneed && kneed <= incl) { selb = (unsigned int)tid; selk = kneed - strict; }
        __syncthreads();
        prefix = (prefix << 8) | selb;
        kneed = selk;
        __syncthreads();
    }
    const unsigned int K32 = prefix;

    #pragma unroll
    for (int t = 0; t < 16; ++t) {
        int c = tid + (t << 8);
        unsigned int kx = skey[c];
        if (kx > K32) {
            int p = atomicAdd(&cnt_gt, 1);
            top_idx[(size_t)row * TOPK + p] = c;
            top_z [(size_t)row * TOPK + p] = finv(kx);
        } else if (kx == K32) {
            int p = atomicAdd(&cnt_eq, 1);
            if (p < 64) eqi[p] = c;
        }
    }
    __syncthreads();
    if (tid == 0) {
        int q = (int)kneed, base = cnt_gt, E = cnt_eq;
        float zv = finv(K32);
        if (E <= 64) {
            for (int s2 = 0; s2 < q; ++s2) {
                int best = 0x7FFFFFFF, bp = 0;
                for (int e = 0; e < E; ++e) { int ix = eqi[e]; if (ix < best) { best = ix; bp = e; } }
                eqi[bp] = 0x7FFFFFFF;
                top_idx[(size_t)row * TOPK + base + s2] = best;
                top_z [(size_t)row * TOPK + base + s2] = zv;
            }
        } else {
            int taken = 0;
            for (int c = 0; c < B && taken < q; ++c)
                if (skey[c] == K32) {
                    top_idx[(size_t)row * TOPK + base + taken] = c;
                    top_z [(size_t)row * TOPK + base + taken] = zv;
                    ++taken;
                }
        }
    }
}

// ---------------------------------------------------------------------------
// kmid: fused reduce + CSR build + single-wave Sinkhorn. Capacity m <= 2048.
// ---------------------------------------------------------------------------
__global__ __launch_bounds__(256) void kmid(const float* __restrict__ rowsum,
                                            const unsigned int* __restrict__ rowmaxk,
                                            const float* __restrict__ top_z,
                                            const int* __restrict__ top_idx,
                                            unsigned int* __restrict__ Mkey_g,
                                            double* __restrict__ base_acc_g,
                                            unsigned int* __restrict__ mcount_g,
                                            unsigned int* __restrict__ meta_g,
                                            float* __restrict__ vout) {
    __shared__ __align__(16) unsigned char SB[94208];
    float*  rcsr_val = (float*)(SB + 0);
    float*  ccsr_val = (float*)(SB + 8192);
    float*  arr      = (float*)(SB + 16384);
    float*  usm      = (float*)(SB + 24576);
    float*  vsm      = (float*)(SB + 32768);
    unsigned* aRowSC = (unsigned*)(SB + 40960);
    unsigned* aColSC = (unsigned*)(SB + 49152);
    unsigned short* rcsr_cid = (unsigned short*)(SB + 57344);
    unsigned short* ccsr_rid = (unsigned short*)(SB + 61440);
    unsigned short* aColJ    = (unsigned short*)(SB + 65536);
    unsigned* colPS  = (unsigned*)(SB + 69632);
    unsigned short* rowCnt = (unsigned short*)(SB + 86016);
    unsigned* colCnt  = (unsigned*)(SB + 0);
    unsigned* rowPS   = (unsigned*)(SB + 24576);
    unsigned* colFill = (unsigned*)(SB + 16384);

    __shared__ double sdbl[4];
    __shared__ unsigned smax4[4];
    __shared__ float sMf;
    __shared__ unsigned mTot;
    __shared__ unsigned wq[4];
    __shared__ unsigned nrS, ncS;

    const int tid = threadIdx.x, lane = tid & 63, wv = tid >> 6;

    // ---------- A: reduce ----------
    {
        double s = 0.0; unsigned mk = 0u;
        #pragma unroll
        for (int t = 0; t < 16; ++t) {
            int i = tid + (t << 8);
            s += (double)rowsum[i];
            unsigned k = rowmaxk[i];
            mk = (k > mk) ? k : mk;
        }
        for (int o = 1; o < 64; o <<= 1) {
            s += __shfl_xor(s, o);
            unsigned om = __shfl_xor(mk, o);
            mk = (om > mk) ? om : mk;
        }
        if (lane == 0) { sdbl[wv] = s; smax4[wv] = mk; }
        if (tid == 0) mTot = 0u;
    }
    __syncthreads();
    if (tid == 0) {
        *base_acc_g = sdbl[0] + sdbl[1] + sdbl[2] + sdbl[3];
        unsigned m2 = max(max(smax4[0], smax4[1]), max(smax4[2], smax4[3]));
        *Mkey_g = m2;
        sMf = finv(m2);
    }
    __syncthreads();
    const float M = sMf;

    // ---------- B1: count survivors + col histogram ----------
    for (int i = tid; i < 4096; i += 256) colCnt[i] = 0u;
    __syncthreads();
    {
        unsigned myTot = 0;
        for (int i = 0; i < 16; ++i) {
            int r = tid * 16 + i;
            const float* tz = top_z + (size_t)r * TOPK;
            const int* tj = top_idx + (size_t)r * TOPK;
            int cnt = 0;
            for (int k = 0; k < TOPK; ++k) {
                float c = fmaxf(M - tz[k], 0.0f);
                if (c >= CPRE) break;
                float e = expf(-(c / OT_EPS_F));
                if (!(e > FLOORK)) break;
                ++cnt;
                atomicAdd(&colCnt[(unsigned)tj[k]], 1u);
            }
            rowCnt[r] = (unsigned short)cnt;
            myTot += (unsigned)cnt;
        }
        atomicAdd(&mTot, myTot);
    }
    __syncthreads();
    const int m = (int)mTot;
    if (tid == 0) { mcount_g[0] = (unsigned)m; meta_g[0] = (m > MCAP) ? 1u : 0u; }
    if (m > MCAP) return;

    // ---------- B2a: row scan ----------
    {
        unsigned pre[16]; unsigned tsum = 0;
        #pragma unroll
        for (int i = 0; i < 16; ++i) {
            unsigned c2 = rowCnt[tid * 16 + i];
            unsigned val = c2 | ((c2 ? 1u : 0u) << 16);
            pre[i] = tsum; tsum += val;
        }
        unsigned sc = tsum;
        for (int o = 1; o < 64; o <<= 1) {
            unsigned n2 = __shfl_up(sc, o);
            if (lane >= o) sc += n2;
        }
        if (lane == 63) wq[wv] = sc;
        __syncthreads();
        unsigned woff = 0;
        for (int w2 = 0; w2 < wv; ++w2) woff += wq[w2];
        unsigned base0 = woff + sc - tsum;
        #pragma unroll
        for (int i = 0; i < 16; ++i) {
            int r = tid * 16 + i;
            unsigned pfx = base0 + pre[i];
            rowPS[r] = pfx;
            unsigned c2 = rowCnt[r];
            if (c2) aRowSC[pfx >> 16] = (pfx & 0xFFFFu) | (c2 << 16);
        }
        if (tid == 255) nrS = (base0 + tsum) >> 16;
    }
    __syncthreads();
    // ---------- B2b: col scan ----------
    {
        unsigned pre[16]; unsigned tsum = 0;
        #pragma unroll
        for (int i = 0; i < 16; ++i) {
            unsigned c2 = colCnt[tid * 16 + i];
            unsigned val = c2 | ((c2 ? 1u : 0u) << 16);
            pre[i] = tsum; tsum += val;
        }
        unsigned sc = tsum;
        for (int o = 1; o < 64; o <<= 1) {
            unsigned n2 = __shfl_up(sc, o);
            if (lane >= o) sc += n2;
        }
        if (lane == 63) wq[wv] = sc;
        __syncthreads();
        unsigned woff = 0;
        for (int w2 = 0; w2 < wv; ++w2) woff += wq[w2];
        unsigned base0 = woff + sc - tsum;
        #pragma unroll
        for (int i = 0; i < 16; ++i) {
            int j = tid * 16 + i;
            unsigned pfx = base0 + pre[i];
            colPS[j] = pfx;
            unsigned c2 = colCnt[j];
            if (c2) {
                unsigned cc = pfx >> 16;
                aColSC[cc] = (pfx & 0xFFFFu) | (c2 << 16);
                aColJ[cc] = (unsigned short)j;
            }
        }
        if (tid == 255) ncS = (base0 + tsum) >> 16;
    }
    __syncthreads();
    // ---------- B3: fill CSR ----------
    for (int i = tid; i < 2048; i += 256) colFill[i] = 0u;
    __syncthreads();
    for (int i = 0; i < 16; ++i) {
        int r = tid * 16 + i;
        int cnt = rowCnt[r];
        if (!cnt) continue;
        unsigned rps = rowPS[r];
        unsigned rptr = rps & 0xFFFFu, rcomp = rps >> 16;
        const float* tz = top_z + (size_t)r * TOPK;
        const int* tj = top_idx + (size_t)r * TOPK;
        for (int k = 0; k < cnt; ++k) {
            float c = fmaxf(M - tz[k], 0.0f);
            float e = expf(-(c / OT_EPS_F));
            float wv2 = e - FLOORK;
            unsigned pos = rptr + (unsigned)k;
            unsigned j = (unsigned)tj[k];
            unsigned cps = colPS[j];
            rcsr_val[pos] = wv2;
            rcsr_cid[pos] = (unsigned short)(cps >> 16);
            unsigned inc = (j & 1u) ? 65536u : 1u;
            unsigned old = atomicAdd(&colFill[j >> 1], inc);
            unsigned prior = (old >> ((j & 1u) * 16u)) & 0xFFFFu;
            unsigned cpos = (cps & 0xFFFFu) + prior;
            ccsr_val[cpos] = wv2;
            ccsr_rid[cpos] = (unsigned short)rcomp;
        }
    }
    __syncthreads();
    // ---------- B4: init scaling tables ----------
    for (int i = tid; i < 2048; i += 256) { usm[i] = 1.0f; vsm[i] = 1.0f; }
    __syncthreads();
    if (wv != 0) return;

    // ---------- D: Sinkhorn (single wave, no barriers) ----------
    const int nr = (int)nrS, nc = (int)ncS;
    float u0 = 1.0f, v0 = 1.0f;
    float SvA = (float)nc;
    for (int it = 0; it < 30; ++it) {
        const float bgu = FLOORK * ((float)(B - nc) * v0 + SvA) + 1e-8f;
        const float u0n = AMASS * rcpf_(bgu);
        for (int e = lane; e < m; e += 64)
            arr[e] = rcsr_val[e] * vsm[rcsr_cid[e]];
        lgkm0();
        float SuP = 0.0f;
        for (int i = lane; i < nr; i += 64) {
            unsigned sc = aRowSC[i];
            unsigned st = sc & 0xFFFFu, ct = sc >> 16;
            float ss = 0.0f;
            #pragma unroll
            for (unsigned k = 0; k < 8; ++k)
                if (k < ct) ss += arr[st + k];
            if (ct > 8u)
                for (unsigned k = 8; k < ct; ++k) ss += arr[st + k];
            float u = AMASS * rcpf_(bgu + ss);
            usm[i] = u; SuP += u;
        }
        const float Su = wsum64(SuP);
        const float bgv = FLOORK * ((float)(B - nr) * u0n + Su) + 1e-8f;
        const float v0n = AMASS * rcpf_(bgv);
        lgkm0();
        for (int e = lane; e < m; e += 64)
            arr[e] = ccsr_val[e] * usm[ccsr_rid[e]];
        lgkm0();
        float SvP = 0.0f; bool moved = false;
        for (int i = lane; i < nc; i += 64) {
            unsigned sc = aColSC[i];
            unsigned st = sc & 0xFFFFu, ct = sc >> 16;
            float ss = 0.0f;
            #pragma unroll
            for (unsigned k = 0; k < 8; ++k)
                if (k < ct) ss += arr[st + k];
            if (ct > 8u)
                for (unsigned k = 8; k < ct; ++k) ss += arr[st + k];
            float vn = AMASS * rcpf_(bgv + ss);
            float vold = vsm[i];
            if (fabsf(vn - vold) > EPS_C * vold) moved = true;
            vsm[i] = vn; SvP += vn;
        }
        SvA = wsum64(SvP);
        const bool conv = (__ballot(moved) == 0ull) &&
                          (fabsf(v0n - v0) <= EPS_C * v0) &&
                          (fabsf(u0n - u0) <= EPS_C * u0);
        u0 = u0n; v0 = v0n;
        lgkm0();
        if (conv) break;
    }
    float4* vo4 = (float4*)vout;
    const float4 fill = make_float4(v0, v0, v0, v0);
    #pragma unroll
    for (int t = 0; t < 16; ++t)
        vo4[lane + (t << 6)] = fill;
    vm0();
    for (int i = lane; i < nc; i += 64)
        vout[aColJ[i]] = vsm[i];
}

// ---------------------------------------------------------------------------
// k4_fb: list-free global Sinkhorn fallback (m > MCAP only). Correctness path.
// ---------------------------------------------------------------------------
__global__ __launch_bounds__(256) void k4_fb(const unsigned int* __restrict__ meta,
                                             const unsigned int* __restrict__ Mkey,
                                             const float* __restrict__ top_z,
                                             const int* __restrict__ top_idx,
                                             float* __restrict__ evals,
                                             float* __restrict__ gv,
                                             float* __restrict__ ga,
                                             float* __restrict__ gb,
                                             float* __restrict__ vout) {
    if (meta[0] == 0u) return;
    __shared__ float red[4];
    __shared__ float bc;
    const int tid = threadIdx.x, lane = tid & 63, wv = tid >> 6;
    const float M = finv(Mkey[0]);

    for (int c = tid; c < B * TOPK; c += 256) {
        float cc = fmaxf(M - top_z[c], 0.0f);
        float e = 0.0f;
        if (cc < CPRE) {
            float t = expf(-(cc / OT_EPS_F));
            if (t > FLOORK) e = t - FLOORK;
        }
        evals[c] = e;
    }
    for (int i = tid; i < B; i += 256) gv[i] = 1.0f;
    __syncthreads();

    for (int it = 0; it < 30; ++it) {
        float s = 0.0f;
        for (int i = tid; i < B; i += 256) { s += gv[i]; ga[i] = 0.0f; }
        for (int o = 1; o < 64; o <<= 1) s += __shfl_xor(s, o);
        if (lane == 0) red[wv] = s;
        __syncthreads();
        if (tid == 0) bc = red[0] + red[1] + red[2] + red[3];
        __syncthreads();
        const float bgu = FLOORK * bc + 1e-8f;
        for (int c = tid; c < B * TOPK; c += 256) {
            float a = evals[c];
            if (a > 0.0f) atomicAdd(&ga[c >> 5], a * gv[top_idx[c]]);
        }
        __syncthreads();
        float su = 0.0f;
        for (int i = tid; i < B; i += 256) { su += AMASS / (bgu + ga[i]); gb[i] = 0.0f; }
        for (int o = 1; o < 64; o <<= 1) su += __shfl_xor(su, o);
        if (lane == 0) red[wv] = su;
        __syncthreads();
        if (tid == 0) bc = red[0] + red[1] + red[2] + red[3];
        __syncthreads();
        const float bgv = FLOORK * bc + 1e-8f;
        for (int c = tid; c < B * TOPK; c += 256) {
            float a = evals[c];
            if (a > 0.0f) {
                float u = AMASS / (bgu + ga[c >> 5]);
                atomicAdd(&gb[top_idx[c]], a * u);
            }
        }
        __syncthreads();
        for (int i = tid; i < B; i += 256) gv[i] = AMASS / (bgv + gb[i]);
        __syncthreads();
    }
    for (int i = tid; i < B; i += 256) vout[i] = gv[i];
}

// ---------------------------------------------------------------------------
// k5: per row: weights = K*v (u cancels), synthetic negative, normalize,
// dot with text row. Unchanged.
// ---------------------------------------------------------------------------
__global__ __launch_bounds__(256) void k5_synth(const int* __restrict__ top_idx,
                                                const float* __restrict__ top_z,
                                                const unsigned int* __restrict__ Mkey,
                                                const float* __restrict__ v,
                                                const float* __restrict__ image,
                                                const float* __restrict__ text,
                                                float* __restrict__ synth_sim) {
    __shared__ float sw[TOPK];
    __shared__ int   sj[TOPK];
    __shared__ float red[4];
    __shared__ float bcast;

    const int row = blockIdx.x, tid = threadIdx.x;
    const int wid = tid >> 6, lane = tid & 63;
    const float M = finv(Mkey[0]);

    if (tid < 64) {
        float wt = 0.0f;
        if (tid < TOPK) {
            int j = top_idx[(size_t)row * TOPK + tid];
            float z = top_z[(size_t)row * TOPK + tid];
            float c = fmaxf(M - z, 0.0f);
            float K = fmaxf(expf(-(c / OT_EPS_F)), FLOORK);
            wt = K * v[j];
            sj[tid] = j;
            sw[tid] = wt;
        }
        float s = wt;
        for (int off = 32; off; off >>= 1) s += __shfl_down(s, off);
        if (tid == 0) bcast = fmaxf(s, 1e-8f);
    }
    __syncthreads();
    if (tid < TOPK) sw[tid] = sw[tid] / bcast;
    __syncthreads();

    float s0 = 0.0f, s1 = 0.0f;
    for (int t = 0; t < TOPK; ++t) {
        float wv2 = sw[t];
        const float* img = image + (size_t)sj[t] * D;
        s0 += wv2 * img[tid];
        s1 += wv2 * img[tid + 256];
    }
    float nn = s0 * s0 + s1 * s1;
    for (int off = 32; off; off >>= 1) nn += __shfl_down(nn, off);
    if (lane == 0) red[wid] = nn;
    __syncthreads();
    float norm2 = red[0] + red[1] + red[2] + red[3];
    float den = sqrtf(norm2) + 1e-8f;
    float p = (s0 / den) * text[(size_t)row * D + tid] +
              (s1 / den) * text[(size_t)row * D + tid + 256];
    __syncthreads();
    for (int off = 32; off; off >>= 1) p += __shfl_down(p, off);
    if (lane == 0) red[wid] = p;
    __syncthreads();
    if (tid == 0) synth_sim[row] = red[0] + red[1] + red[2] + red[3];
}

// ---------------------------------------------------------------------------
// k78: median of ratio via radix select, then gate + final combine. Unchanged.
// ---------------------------------------------------------------------------
__global__ __launch_bounds__(256) void k78_final(const float* __restrict__ ratio,
                                                 const float* __restrict__ synth_sim,
                                                 const double* __restrict__ base_acc,
                                                 float* __restrict__ out) {
    __shared__ unsigned int skey[B];
    __shared__ unsigned int histm[4 * 257 + 4];
    __shared__ unsigned int selb, selk;
    __shared__ double rs[4];
    __shared__ float rg[4];

    const int tid = threadIdx.x, wid = tid >> 6, lane = tid & 63;

    #pragma unroll
    for (int t = 0; t < 16; ++t) {
        int c = tid + (t << 8);
        skey[c] = fkey(ratio[c]);
    }
    __syncthreads();

    unsigned int prefix = 0, kneed = 2048;
    for (int r = 0; r < 4; ++r) {
        for (int i = tid; i < 4 * 257 + 4; i += 256) histm[i] = 0;
        __syncthreads();
        const int shift = 24 - 8 * r;
        unsigned int cb = 0xFFFFFFFFu, cc = 0;
        #pragma unroll
        for (int t = 0; t < 16; ++t) {
            unsigned int kx = skey[tid + (t << 8)];
            bool part = (r == 0) || ((kx >> (32 - 8 * r)) == prefix);
            if (part) {
                unsigned int bin = (kx >> shift) & 255u;
                if (bin == cb) ++cc;
                else {
                    if (cc) atomicAdd(&histm[wid * 257 + cb], cc);
                    cb = bin; cc = 1;
                }
            }
        }
        if (cc) atomicAdd(&histm[wid * 257 + cb], cc);
        __syncthreads();
        unsigned int h = histm[tid] + histm[257 + tid] + histm[514 + tid] + histm[771 + tid];
        unsigned int s = h;
        for (int off = 1; off < 64; off <<= 1) {
            unsigned int o = __shfl_down(s, off);
            if (lane + off < 64) s += o;
        }
        if (lane == 0) histm[1028 + wid] = s;
        __syncthreads();
        unsigned int coarse = 0;
        for (int w = wid + 1; w < 4; ++w) coarse += histm[1028 + w];
        unsigned int incl = s + coarse, strict = incl - h;
        if (strict < kneed && kneed <= incl) { selb = (unsigned int)tid; selk = kneed - strict; }
        __syncthreads();
        prefix = (prefix << 8) | selb;
        kneed = selk;
        __syncthreads();
    }
    const unsigned int KA = prefix;
    const unsigned int g = 2048u - kneed;

    unsigned int ec = 0, mb = 0;
    #pragma unroll
    for (int t = 0; t < 16; ++t) {
        unsigned int kx = skey[tid + (t << 8)];
        if (kx == KA) ++ec;
        else if (kx < KA && kx > mb) mb = kx;
    }
    for (int off = 1; off < 64; off <<= 1) {
        ec += __shfl_xor(ec, off);
        unsigned int o = __shfl_xor(mb, off);
        mb = (o > mb) ? o : mb;
    }
    __syncthreads();
    if (lane == 0) { histm[wid] = ec; histm[8 + wid] = mb; }
    __syncthreads();
    unsigned int E  = histm[0] + histm[1] + histm[2] + histm[3];
    unsigned int MB = max(max(histm[8], histm[9]), max(histm[10], histm[11]));
    unsigned int KB = (g + E >= 2049u) ? KA : MB;
    const float scale = 0.5f * (finv(KA) + finv(KB));

    double lsd = 0.0; float gs = 0.0f;
    #pragma unroll
    for (int t = 0; t < 16; ++t) {
        float sl = scale * synth_sim[tid + (t << 8)];
        if (sl > -0.05f) { gs += 1.0f; lsd += (double)softplusf(sl); }
    }
    for (int off = 1; off < 64; off <<= 1) {
        lsd += __shfl_xor(lsd, off);
        gs  += __shfl_xor(gs, off);
    }
    if (lane == 0) { rs[wid] = lsd; rg[wid] = gs; }
    __syncthreads();
    if (tid == 0) {
        double L = rs[0] + rs[1] + rs[2] + rs[3];
        float  G = rg[0] + rg[1] + rg[2] + rg[3];
        double base = base_acc[0] / ((double)B * (double)B);
        double synth = (G > 0.0f) ? (L / ((double)G + 1e-8)) : 0.0;
        out[0] = (float)(base + 0.5 * synth);
    }
}

extern "C" void kernel_launch(void* const* d_in, const int* in_sizes, int n_in,
                              void* d_out, int out_size, void* d_ws, size_t ws_size,
                              hipStream_t stream) {
    const float* logits = (const float*)d_in[0];
    const float* text   = (const float*)d_in[1];
    const float* image  = (const float*)d_in[2];
    const float* bias   = (const float*)d_in[3];

    char* ws = (char*)d_ws;
    double*       base_acc = (double*)(ws + 0);
    unsigned int* mcount   = (unsigned int*)(ws + 8);
    unsigned int* Mkey     = (unsigned int*)(ws + 12);
    unsigned int* meta     = (unsigned int*)(ws + 16);
    unsigned int* flags    = (unsigned int*)(ws + 64);            // 16 KB
    float*        rowsum   = (float*)(ws + 64 + 16384);
    unsigned int* rowmaxk  = (unsigned int*)(rowsum + B);
    float*        v        = (float*)(rowmaxk + B);
    float*        sim      = v + B;
    float*        ratio    = sim + B;
    float*        gv       = ratio + B;
    float*        ga       = gv + B;
    float*        gb       = ga + B;
    int*          top_idx  = (int*)(gb + B);
    float*        top_z    = (float*)(top_idx + (size_t)B * TOPK);
    float*        evals    = (float*)(top_z + (size_t)B * TOPK);

    // zero: header + flags (k1_fallback gating)
    hipMemsetAsync(ws, 0, 64 + 16384, stream);

    k1_row     <<<B / 4, 256, 0, stream>>>(logits, text, image, bias, rowsum, rowmaxk,
                                           top_idx, top_z, ratio, flags);
    k1_fallback<<<B, 256, 0, stream>>>(logits, bias, flags, top_idx, top_z);
    kmid       <<<1, 256, 0, stream>>>(rowsum, rowmaxk, top_z, top_idx, Mkey, base_acc,
                                       mcount, meta, v);
    k4_fb      <<<1, 256, 0, stream>>>(meta, Mkey, top_z, top_idx, evals, gv, ga, gb, v);
    k5_synth   <<<B, 256, 0, stream>>>(top_idx, top_z, Mkey, v, image, text, sim);
    k78_final  <<<1, 256, 0, stream>>>(ratio, sim, base_acc, (float*)d_out);
}